// Round 10
// baseline (418.943 us; speedup 1.0000x reference)
//
#include <hip/hip_runtime.h>
#include <hip/hip_bf16.h>

typedef __attribute__((ext_vector_type(8))) short short8;
typedef __attribute__((ext_vector_type(4))) float f32x4;
typedef __hip_bfloat16 bf16;
typedef unsigned short ushort;

__device__ __forceinline__ ushort f2b(float v) {
    bf16 h = __float2bfloat16(v);
    return *reinterpret_cast<ushort*>(&h);
}
__device__ __forceinline__ float b2f(ushort u) {
    return __uint_as_float((unsigned)u << 16);
}

#define GLD16(lds, gp) __builtin_amdgcn_global_load_lds( \
    (const __attribute__((address_space(1))) void*)(gp), \
    (__attribute__((address_space(3))) void*)(lds), 16, 0, 0)

// XCD-affinity swizzle (R3-verified: gate FETCH 64.6->37MB). Bijective when
// gridDim.y%8==0; swizzles (bx,by) within each z-slice.
__device__ __forceinline__ void xcd_swizzle(int& bx, int& by) {
    if ((gridDim.y & 7) == 0) {
        const int id = bx + gridDim.x * by;
        const int xcd = id & 7, slot = id >> 3;
        by = xcd * (gridDim.y >> 3) + slot / gridDim.x;
        bx = slot - (slot / gridDim.x) * gridDim.x;
    }
}

// ---------------------------------------------------------------------------
// bf16 MFMA GEMM: C = alpha * A @ B^T (+ bias) with fused epilogues.
// R12 staged core. Coalesced row-major [r][32] chunk-rotation LDS layout
// (bank-conflict 0). TM=64: BK=64 2-plane buffers; TM=128: BK=32.
// nry>0 flattens batch into y so the XCD swizzle pins batches to XCD L2s.
// R15 BD=true: B never staged - fragments read DIRECT from global per phase.
// Fragment load = 16 rows x 64B fully coalesced (4 lanes/line), same L2
// traffic as staging, minus the LDS round-trip. ONLY for L2-hot <=1MB B
// panels (weights / per-batch Bcat). NOT R4's failure (that was direct on
// cold 25MB A panels too -> 4x line over-read). Math order identical.
// EPI 0: plain.
// EPI 4: QKV head-scatter: C=Qb, px=Kb, py=VT
// EPI 5: KV split: C=Kc [b][n][512], py=v_iT [b][hd][768]
// EPI 6: dual write: C normal + py transposed
// EPI 8: step1+vb-fold: C normal; cols>=1024 also write 16x-replicated
//        transposed panel into py (Bcat k-concat region), sE=batch stride.
// ---------------------------------------------------------------------------
template<typename OutT, int EPI, int TM, bool BD = false>
__global__ __launch_bounds__(256) void gemm_bf16(
    const bf16* __restrict__ A, const bf16* __restrict__ B, OutT* __restrict__ C,
    int K, int lda, int ldb, int ldc, long sA, long sB, long sC,
    float alpha, const float* __restrict__ bias,
    int lda2, long sA2, int eld, long sE,
    bf16* __restrict__ px, bf16* __restrict__ py, int nry)
{
    constexpr int RT = TM / 32;              // row MFMA-tiles per wave
    constexpr int PLA = TM * 32;             // halfwords per 32-k A plane
    constexpr int PLB = 128 * 32;
    constexpr int NP = (TM == 64) ? 4 : 2;   // planes total (2 bufs x {2,1})
    constexpr int NBS = BD ? 16 : NP * PLB;
    __shared__ __align__(16) bf16 As[NP * PLA];
    __shared__ __align__(16) bf16 Bs[NBS];

    const int t = threadIdx.x;
    const int w = t >> 6, lane = t & 63;
    const int wr = w >> 1, wc = w & 1;
    const int lr = lane & 15, kc4 = lane >> 4;
    const int qr = lane >> 2;                              // row within 16-row slice
    const int kcr = ((lane & 3) - ((lane >> 3) & 3)) & 3;  // rotated global k-chunk
    int bx = blockIdx.x, by = blockIdx.y;
    xcd_swizzle(bx, by);
    int zidx, row0;
    if (nry > 0) { zidx = by / nry; row0 = (by % nry) * TM; }
    else         { zidx = blockIdx.z; row0 = by * TM; }
    const int col0 = bx * 128;

    const bf16* Ab = A + (size_t)zidx * sA + (size_t)row0 * lda;
    const bf16* Bb = B + (size_t)zidx * sB + (size_t)col0 * ldb;

    // staging: each GLD16 covers 16 rows x 64B (4 lanes/row, coalesced)
    const bf16* ga0; const bf16* ga1 = nullptr;
    if constexpr (TM == 64) {
        ga0 = Ab + (size_t)(w * 16 + qr) * lda + kcr * 8;
    } else {
        ga0 = Ab + (size_t)(w * 32 + qr) * lda + kcr * 8;
        ga1 = Ab + (size_t)(w * 32 + 16 + qr) * lda + kcr * 8;
    }
    const bf16* gb0 = Bb + (size_t)(w * 32 + qr) * ldb + kcr * 8;
    const bf16* gb1 = Bb + (size_t)(w * 32 + 16 + qr) * ldb + kcr * 8;
    bf16* lA0; bf16* lA1 = nullptr;
    if constexpr (TM == 64) { lA0 = &As[w * 512]; }
    else                    { lA0 = &As[w * 1024]; lA1 = &As[w * 1024 + 512]; }
    bf16* lB0 = nullptr; bf16* lB1 = nullptr;
    if constexpr (!BD) { lB0 = &Bs[w * 1024]; lB1 = &Bs[w * 1024 + 512]; }

    f32x4 acc[RT][4] = {};

    const int cSw = ((kc4 + ((lr >> 1) & 3)) & 3) * 8;     // swizzled chunk offset
    const bf16* ApBase = &As[(wr * (TM / 2) + lr) * 32 + cSw];
    const bf16* BpBase = nullptr;
    if constexpr (!BD) BpBase = &Bs[(wc * 64 + lr) * 32 + cSw];
    // BD: per-lane direct B fragment base (+ j*16*ldb + kk)
    const bf16* gBf = Bb + (size_t)(wc * 64 + lr) * ldb + kc4 * 8;

    auto stageP = [&](int plane, int ko) {
        GLD16(lA0 + plane * PLA, ga0 + ko);
        if constexpr (TM == 128) GLD16(lA1 + plane * PLA, ga1 + ko);
        if constexpr (!BD) {
            GLD16(lB0 + plane * PLB, gb0 + ko);
            GLD16(lB1 + plane * PLB, gb1 + ko);
        }
    };
    auto compP = [&](int plane, int kk) {
        const bf16* Ap = ApBase + plane * PLA;
        short8 af[RT], bfr[4];
#pragma unroll
        for (int i = 0; i < RT; ++i) af[i]  = *(const short8*)(Ap + i * 512);
        if constexpr (BD) {
#pragma unroll
            for (int j = 0; j < 4; ++j)
                bfr[j] = *(const short8*)(gBf + (size_t)j * 16 * ldb + kk);
        } else {
            const bf16* Bp = BpBase + plane * PLB;
#pragma unroll
            for (int j = 0; j < 4; ++j) bfr[j] = *(const short8*)(Bp + j * 512);
        }
#pragma unroll
        for (int i = 0; i < RT; ++i)
#pragma unroll
            for (int j = 0; j < 4; ++j)
                acc[i][j] = __builtin_amdgcn_mfma_f32_16x16x32_bf16(af[i], bfr[j], acc[i][j], 0, 0, 0);
    };

    if constexpr (TM == 64) {
        stageP(0, 0); stageP(1, 32);        // prologue: buffer 0, planes 0..1
        int buf = 0;
        for (int k0 = 0; k0 < K; k0 += 64) {   // K % 64 == 0 at all call sites
            __syncthreads();                   // cur buf staged; other buf free
            if (k0 + 64 < K) {
                stageP((buf ^ 1) * 2,     k0 + 64);
                stageP((buf ^ 1) * 2 + 1, k0 + 96);
            }
            compP(buf * 2, k0); compP(buf * 2 + 1, k0 + 32);
            buf ^= 1;
        }
    } else {
        stageP(0, 0);
        int buf = 0;
        for (int k0 = 0; k0 < K; k0 += 32) {
            __syncthreads();
            if (k0 + 32 < K) stageP(buf ^ 1, k0 + 32);
            compP(buf, k0);
            buf ^= 1;
        }
    }

    if constexpr (EPI == 4) {
        const int sec = bx >> 2;                    // 0=q 1=k 2=v
        const int h0 = (bx & 3) * 2;
        const int b  = by / 6;
        const int n0 = (by % 6) * TM;
        bf16* dq = (bf16*)C;
#pragma unroll
        for (int j = 0; j < 4; ++j) {
            const int col = wc * 64 + j * 16 + lr;
            const int h = h0 + (col >> 6), hd = col & 63;
            const size_t bh = (size_t)b * 8 + h;
#pragma unroll
            for (int i = 0; i < RT; ++i) {
                const int n = n0 + wr * (TM / 2) + i * 16 + kc4 * 4;
                if (sec == 2) {
                    __align__(8) ushort o[4];
#pragma unroll
                    for (int r = 0; r < 4; ++r) o[r] = f2b(acc[i][j][r]);
                    *(int2*)&py[(bh * 64 + hd) * 768 + n] = *(const int2*)o;
                } else {
                    bf16* d = (sec == 0) ? dq : px;
#pragma unroll
                    for (int r = 0; r < 4; ++r)
                        d[(bh * 768 + n + r) * 64 + hd] = __float2bfloat16(acc[i][j][r]);
                }
            }
        }
        return;
    } else if constexpr (EPI == 5) {
        const int b  = by / 6;
        const int n0 = (by % 6) * TM;
#pragma unroll
        for (int j = 0; j < 4; ++j) {
            const int col = col0 + wc * 64 + j * 16 + lr;
#pragma unroll
            for (int i = 0; i < RT; ++i) {
                const int n = n0 + wr * (TM / 2) + i * 16 + kc4 * 4;
                if (col < 512) {
#pragma unroll
                    for (int r = 0; r < 4; ++r)
                        ((bf16*)C)[((size_t)b * 768 + n + r) * 512 + col] = __float2bfloat16(acc[i][j][r]);
                } else {
                    __align__(8) ushort o[4];
#pragma unroll
                    for (int r = 0; r < 4; ++r) o[r] = f2b(acc[i][j][r]);
                    *(int2*)&py[((size_t)b * 512 + (col - 512)) * 768 + n] = *(const int2*)o;
                }
            }
        }
        return;
    }

    OutT* Cb = C + (size_t)zidx * sC;
#pragma unroll
    for (int j = 0; j < 4; ++j) {
        const int col = col0 + wc * 64 + j * 16 + lr;
        const float bv = bias ? bias[col] : 0.f;
#pragma unroll
        for (int i = 0; i < RT; ++i) {
            const int rb = row0 + wr * (TM / 2) + i * 16 + kc4 * 4;
            if constexpr (EPI == 6) {
                __align__(8) ushort o[4];
#pragma unroll
                for (int r = 0; r < 4; ++r) {
                    o[r] = f2b(alpha * acc[i][j][r]);
                    Cb[(size_t)(rb + r) * ldc + col] = __float2bfloat16(alpha * acc[i][j][r]);
                }
                *(int2*)&py[(size_t)zidx * sE + (size_t)col * eld + rb] = *(const int2*)o;
            } else if constexpr (EPI == 8) {
                __align__(8) ushort o[4];
#pragma unroll
                for (int r = 0; r < 4; ++r) {
                    o[r] = f2b(acc[i][j][r]);
                    Cb[(size_t)(rb + r) * ldc + col] = __float2bfloat16(acc[i][j][r]);
                }
                if (col >= 1024) {
                    const size_t tb = (size_t)(col - 1024) * 512 + 256 + rb;
#pragma unroll
                    for (int b2 = 0; b2 < 16; ++b2)
                        *(int2*)&py[(size_t)b2 * sE + tb] = *(const int2*)o;
                }
            } else {
#pragma unroll
                for (int r = 0; r < 4; ++r) {
                    const int row = rb + r;
                    float v = alpha * acc[i][j][r] + bv;
                    if constexpr (sizeof(OutT) == 2)
                        Cb[(size_t)row * ldc + col] = __float2bfloat16(v);
                    else
                        Cb[(size_t)row * ldc + col] = v;
                }
            }
        }
    }
}

// ---------------------------------------------------------------------------
// S2/S3 GEMM with FUSED row-softmax (R14; verified R8). Block = 64 rows x
// 256 cols = full softmax row. z=0: S2 = sm(scale * x1 @ aib0^T); z=1:
// S3 = sm(scale * x2 @ G^T). Two-stage max exact; exp split <=2 ulp.
// Output direct to Sb_cat bf16 K-concat layout. LDS 41KB.
// ---------------------------------------------------------------------------
__global__ __launch_bounds__(256) void gemm_sm(
    const bf16* __restrict__ A0, const bf16* __restrict__ B0,
    const bf16* __restrict__ A1, const bf16* __restrict__ B1,
    bf16* __restrict__ Y, float alpha)
{
    constexpr int PLA = 64 * 32;     // 2048 hw
    constexpr int PLB = 256 * 32;    // 8192 hw
    __shared__ __align__(16) bf16 As[2 * PLA];
    __shared__ __align__(16) bf16 Bs[2 * PLB];
    __shared__ float sc[2][2][2][32];   // [wr][wc][{m,s}][row-in-32]

    const int t = threadIdx.x;
    const int w = t >> 6, lane = t & 63;
    const int wr = w >> 1, wc = w & 1;
    const int lr = lane & 15, kc4 = lane >> 4;
    const int qr = lane >> 2;
    const int kcr = ((lane & 3) - ((lane >> 3) & 3)) & 3;
    int bx = blockIdx.x, by = blockIdx.y;
    xcd_swizzle(bx, by);
    const int b = by / 12, row0 = (by % 12) * 64;
    const int half = blockIdx.z;

    const bf16* Ab; int lda; const bf16* Bb;
    if (half == 0) {
        Ab = A0 + (size_t)b * (768L * 512) + (size_t)row0 * 512;  lda = 512;
        Bb = B0 + (size_t)b * (256L * 512);
    } else {
        Ab = A1 + (size_t)b * (768L * 1024) + (size_t)row0 * 1024; lda = 1024;
        Bb = B1;
    }

    const bf16* ga0 = Ab + (size_t)(w * 16 + qr) * lda + kcr * 8;
    const bf16* gb0 = Bb + (size_t)(w * 32 + qr) * 512 + kcr * 8;
    const bf16* gb1 = Bb + (size_t)(w * 32 + 16 + qr) * 512 + kcr * 8;
    const bf16* gb2 = Bb + (size_t)(128 + w * 32 + qr) * 512 + kcr * 8;
    const bf16* gb3 = Bb + (size_t)(128 + w * 32 + 16 + qr) * 512 + kcr * 8;
    bf16* lA0 = &As[w * 512];
    bf16* lB0 = &Bs[w * 1024];        bf16* lB1 = &Bs[w * 1024 + 512];
    bf16* lB2 = &Bs[4096 + w * 1024]; bf16* lB3 = &Bs[4096 + w * 1024 + 512];

    f32x4 acc[2][8] = {};

    const int cSw = ((kc4 + ((lr >> 1) & 3)) & 3) * 8;
    const bf16* ApBase = &As[(wr * 32 + lr) * 32 + cSw];
    const bf16* BpBase = &Bs[(wc * 128 + lr) * 32 + cSw];

    auto stageP = [&](int pl, int ko) {
        GLD16(lA0 + pl * PLA, ga0 + ko);
        GLD16(lB0 + pl * PLB, gb0 + ko); GLD16(lB1 + pl * PLB, gb1 + ko);
        GLD16(lB2 + pl * PLB, gb2 + ko); GLD16(lB3 + pl * PLB, gb3 + ko);
    };
    auto compP = [&](int pl) {
        const bf16* Ap = ApBase + pl * PLA;
        const bf16* Bp = BpBase + pl * PLB;
        short8 af[2], bfr[8];
#pragma unroll
        for (int i = 0; i < 2; ++i) af[i] = *(const short8*)(Ap + i * 512);
#pragma unroll
        for (int j = 0; j < 8; ++j) bfr[j] = *(const short8*)(Bp + j * 512);
#pragma unroll
        for (int i = 0; i < 2; ++i)
#pragma unroll
            for (int j = 0; j < 8; ++j)
                acc[i][j] = __builtin_amdgcn_mfma_f32_16x16x32_bf16(af[i], bfr[j], acc[i][j], 0, 0, 0);
    };

    stageP(0, 0);
    int buf = 0;
    for (int k0 = 0; k0 < 512; k0 += 32) {
        __syncthreads();
        if (k0 + 32 < 512) stageP(buf ^ 1, k0 + 32);
        compP(buf);
        buf ^= 1;
    }

    // ---- fused softmax over the 256-col rows ----
    float mloc[2][4], sloc[2][4], scl[2][4];
#pragma unroll
    for (int i = 0; i < 2; ++i)
#pragma unroll
        for (int e = 0; e < 4; ++e) {
            float m = alpha * acc[i][0][e];
#pragma unroll
            for (int j = 1; j < 8; ++j) m = fmaxf(m, alpha * acc[i][j][e]);
#pragma unroll
            for (int o = 1; o < 16; o <<= 1) m = fmaxf(m, __shfl_xor(m, o));
            mloc[i][e] = m;
            float s = 0.f;
#pragma unroll
            for (int j = 0; j < 8; ++j) {
                const float p = __expf(alpha * acc[i][j][e] - m);
                acc[i][j][e] = p;
                s += p;
            }
#pragma unroll
            for (int o = 1; o < 16; o <<= 1) s += __shfl_xor(s, o);
            sloc[i][e] = s;
            if (lr == 0) {
                sc[wr][wc][0][i * 16 + kc4 * 4 + e] = m;
                sc[wr][wc][1][i * 16 + kc4 * 4 + e] = s;
            }
        }
    __syncthreads();
#pragma unroll
    for (int i = 0; i < 2; ++i)
#pragma unroll
        for (int e = 0; e < 4; ++e) {
            const float m2 = sc[wr][wc ^ 1][0][i * 16 + kc4 * 4 + e];
            const float s2 = sc[wr][wc ^ 1][1][i * 16 + kc4 * 4 + e];
            const float M = fmaxf(mloc[i][e], m2);
            const float S = sloc[i][e] * __expf(mloc[i][e] - M) + s2 * __expf(m2 - M);
            scl[i][e] = __expf(mloc[i][e] - M) / S;
        }
    bf16* dst = Y + ((size_t)b * 768 + row0) * 512 + half * 256 + wc * 128;
#pragma unroll
    for (int i = 0; i < 2; ++i)
#pragma unroll
        for (int j = 0; j < 8; ++j)
#pragma unroll
            for (int e = 0; e < 4; ++e)
                dst[(size_t)(wr * 32 + i * 16 + kc4 * 4 + e) * 512 + j * 16 + lr] =
                    __float2bfloat16(acc[i][j][e] * scl[i][e]);
}

// ---------------------------------------------------------------------------
// Fused gate GEMM (steps 11+12), grid (4,192) = 768 (3 blk/CU).
// R13 column-split wave map. R15: M-operand (W_m, 512KB L2-hot) read DIRECT
// from global (coalesced 16-row x 64B fragment loads) - no M staging, no M
// LDS. LDS pipe -~30% (was the measured bottleneck: ~610cyc LDS vs 240cyc
// MFMA per CU-phase). LDS 40KB -> 24KB. Math order identical.
// ---------------------------------------------------------------------------
__global__ __launch_bounds__(256) void gemm_gate(
    const bf16* __restrict__ A, const bf16* __restrict__ Bf,
    const bf16* __restrict__ Bm, bf16* __restrict__ Cout,
    const float* __restrict__ bias_f, const float* __restrict__ bias_m,
    const bf16* __restrict__ x1b)
{
    constexpr int AHW = 64 * 32;
    constexpr int BHW = 128 * 32;
    __shared__ __align__(16) bf16 As[2 * AHW];
    __shared__ __align__(16) bf16 FsS[2 * BHW];

    const int t = threadIdx.x;
    const int w = t >> 6, lane = t & 63;
    const int lr = lane & 15, kc4 = lane >> 4;
    const int qr = lane >> 2;
    const int kcr = ((lane & 3) - ((lane >> 3) & 3)) & 3;
    int bx = blockIdx.x, by = blockIdx.y;
    xcd_swizzle(bx, by);
    const int row0 = by * 64, col0 = bx * 128;

    const bf16* ga0 = A  + (size_t)(row0 + w * 16 + qr) * 1024 + kcr * 8;
    const bf16* gf0 = Bf + (size_t)(col0 + w * 32 + qr) * 1024 + kcr * 8;
    const bf16* gf1 = Bf + (size_t)(col0 + w * 32 + 16 + qr) * 1024 + kcr * 8;
    bf16* lA0 = &As[w * 512];
    bf16* lF0 = &FsS[w * 1024]; bf16* lF1 = &FsS[w * 1024 + 512];

    f32x4 acc1[4][2] = {};   // fg   [row-tile][col-tile]
    f32x4 acc2[4][2] = {};   // hm

    const int cSw = ((kc4 + ((lr >> 1) & 3)) & 3) * 8;
    // wave reads ALL 4 row-tiles of A, its own 2 col-tiles of F
    const bf16* ApBase = &As[lr * 32 + cSw];                       // +i*512
    const bf16* FpBase = &FsS[(w * 32 + lr) * 32 + cSw];           // +j*512
    // direct M fragment base: + j*16*512 + kk
    const bf16* gMf = Bm + (size_t)(col0 + w * 32 + lr) * 512 + kc4 * 8;

    GLD16(lA0, ga0);
    GLD16(lF0, gf0); GLD16(lF1, gf1);

    auto step = [&](int kk, int rd, int st) {
        __syncthreads();
        const int kn = kk + 32;
        if (kn < 1024) {
            GLD16(lA0 + st * AHW, ga0 + kn);
            GLD16(lF0 + st * BHW, gf0 + kn);
            GLD16(lF1 + st * BHW, gf1 + kn);
        }
        const bf16* Ap = ApBase + rd * AHW;
        const bf16* Fp = FpBase + rd * BHW;
        short8 af[4], ff[2];
#pragma unroll
        for (int i = 0; i < 4; ++i) af[i] = *(const short8*)(Ap + i * 512);
#pragma unroll
        for (int j = 0; j < 2; ++j) ff[j] = *(const short8*)(Fp + j * 512);
#pragma unroll
        for (int i = 0; i < 4; ++i)
#pragma unroll
            for (int j = 0; j < 2; ++j)
                acc1[i][j] = __builtin_amdgcn_mfma_f32_16x16x32_bf16(af[i], ff[j], acc1[i][j], 0, 0, 0);
        if (kk < 512) {
            short8 mf[2];
#pragma unroll
            for (int j = 0; j < 2; ++j)
                mf[j] = *(const short8*)(gMf + (size_t)j * 16 * 512 + kk);
#pragma unroll
            for (int i = 0; i < 4; ++i)
#pragma unroll
                for (int j = 0; j < 2; ++j)
                    acc2[i][j] = __builtin_amdgcn_mfma_f32_16x16x32_bf16(af[i], mf[j], acc2[i][j], 0, 0, 0);
        }
    };

    for (int k0 = 0; k0 < 1024; k0 += 64) {
        step(k0, 0, 1);
        step(k0 + 32, 1, 0);
    }

    const ushort* xr = (const ushort*)x1b;
#pragma unroll
    for (int j = 0; j < 2; ++j) {
        const int col = col0 + w * 32 + j * 16 + lr;
        const float bvf = bias_f[col], bvm = bias_m[col];
#pragma unroll
        for (int i = 0; i < 4; ++i) {
            const int rb = row0 + i * 16 + kc4 * 4;
#pragma unroll
            for (int r = 0; r < 4; ++r) {
                const int row = rb + r;
                const float sig = 1.f / (1.f + __expf(-(acc1[i][j][r] + bvf)));
                const float rr = b2f(xr[(size_t)row * 512 + col]) + (acc2[i][j][r] + bvm) * sig;
                Cout[(size_t)row * 512 + col] = __float2bfloat16(rr > 0.f ? rr : 0.f);
            }
        }
    }
}

// ---------------------------------------------------------------------------
// R15: ALL weight transposes in ONE dispatch. z-encoded job table:
// z 0..2: Wqkv_i / Wqkv_b / W_QKV [512,1536] -> Wt4[z] [1536,512]
// z 3   : W_f [1024,512] -> Wt_f [512,1024]
// z 4,5 : W_m / W_proj [512,512] -> Wt_mp[z-4]
// Grid (24,16,6); out-of-range blocks exit uniformly before the barrier.
// ---------------------------------------------------------------------------
__global__ __launch_bounds__(256) void k_transpose_all(
    const float* __restrict__ Wi, const float* __restrict__ Wb,
    const float* __restrict__ Wq, const float* __restrict__ Wf,
    const float* __restrict__ Wm, const float* __restrict__ Wp,
    bf16* __restrict__ dWt4, bf16* __restrict__ dWf, bf16* __restrict__ dWmp)
{
    const int z = blockIdx.z;
    const float* src; bf16* dst; int sld, dld, xmax, ymax;
    if (z < 3)      { src = (z == 0) ? Wi : (z == 1) ? Wb : Wq;
                      dst = dWt4 + (size_t)z * 1536 * 512;
                      sld = 1536; dld = 512; xmax = 24; ymax = 8; }
    else if (z == 3){ src = Wf; dst = dWf; sld = 512; dld = 1024; xmax = 8; ymax = 16; }
    else            { src = (z == 4) ? Wm : Wp;
                      dst = dWmp + (size_t)(z - 4) * 512 * 512;
                      sld = 512; dld = 512; xmax = 8; ymax = 8; }
    if (blockIdx.x >= (unsigned)xmax || blockIdx.y >= (unsigned)ymax) return;

    __shared__ float tile[64][65];
    const int t = threadIdx.x;
    const int c0 = blockIdx.x * 64, r0 = blockIdx.y * 64;
    {
        const int r = t >> 2, cq = (t & 3) * 16;
        const float* sp = src + (size_t)(r0 + r) * sld + c0 + cq;
#pragma unroll
        for (int u = 0; u < 16; u += 4) {
            float4 v = *(const float4*)(sp + u);
            tile[r][cq + u]     = v.x; tile[r][cq + u + 1] = v.y;
            tile[r][cq + u + 2] = v.z; tile[r][cq + u + 3] = v.w;
        }
    }
    __syncthreads();
    const int c = t >> 2, rq = (t & 3) * 16;
    __align__(16) ushort ob[16];
#pragma unroll
    for (int u = 0; u < 16; ++u) ob[u] = f2b(tile[rq + u][c]);
    bf16* dp = dst + (size_t)(c0 + c) * dld + r0 + rq;
    *(int4*)dp       = *(const int4*)&ob[0];
    *(int4*)(dp + 8) = *(const int4*)&ob[8];
}

// input casts in one dispatch (z selects job). z==3: strided read of
// Wqkv_j[:, :512] (f32 ld 1536) -> Wj_bf [512][512] bf16 (for the G trick).
__global__ __launch_bounds__(256) void k_cast3(const float* __restrict__ x1,
    const float* __restrict__ x2, const float* __restrict__ zb,
    const float* __restrict__ wj,
    bf16* __restrict__ d1, bf16* __restrict__ d2, bf16* __restrict__ d3,
    bf16* __restrict__ d4)
{
    const int z = blockIdx.z;
    const float* src; bf16* dst; int ld; float scale; int n;
    if (z == 0)      { src = x1; dst = d1; ld = 512;  scale = 1.f;  n = 6291456; }
    else if (z == 1) { src = x2; dst = d2; ld = 1024; scale = 1.f;  n = 6291456; }
    else if (z == 2) { src = zb; dst = d3; ld = 512;  scale = 0.2f; n = 131072;  }
    else             { src = wj; dst = d4; ld = 512;  scale = 1.f;  n = 262144;  }
    int i = (blockIdx.x * 256 + threadIdx.x) * 8;
    if (i >= n) return;
    int si = i;
    if (z == 3) si = (i >> 9) * 1536 + (i & 511);
    float4 a = *(const float4*)(src + si), b = *(const float4*)(src + si + 4);
    __align__(16) ushort o[8];
    o[0] = f2b(a.x * scale); o[1] = f2b(a.y * scale); o[2] = f2b(a.z * scale); o[3] = f2b(a.w * scale);
    o[4] = f2b(b.x * scale); o[5] = f2b(b.y * scale); o[6] = f2b(b.z * scale); o[7] = f2b(b.w * scale);
    int row = i >> 9, col = i & 511;
    *(int4*)(dst + (size_t)row * ld + col) = *(const int4*)o;
}

// ---------------------------------------------------------------------------
// Wave-per-row softmax f32 -> bf16. 4 rows/block (one per wave), no barriers.
// ---------------------------------------------------------------------------
template<int COLS, int MODE>
__global__ __launch_bounds__(256) void softmax_wave(const float* __restrict__ X,
                                                    bf16* __restrict__ Y)
{
    const int wv = threadIdx.x >> 6, lane = threadIdx.x & 63;
    const long row = (long)blockIdx.x * 4 + wv;
    const float* src = X + row * COLS;
    constexpr int V = COLS / 64;
    float v[V];
#pragma unroll
    for (int i = 0; i < V; ++i) v[i] = src[lane + i * 64];
    float m = v[0];
#pragma unroll
    for (int i = 1; i < V; ++i) m = fmaxf(m, v[i]);
#pragma unroll
    for (int o = 32; o; o >>= 1) m = fmaxf(m, __shfl_xor(m, o));
    float s = 0.f;
#pragma unroll
    for (int i = 0; i < V; ++i) { v[i] = __expf(v[i] - m); s += v[i]; }
#pragma unroll
    for (int o = 32; o; o >>= 1) s += __shfl_xor(s, o);
    const float inv = 1.f / s;
    bf16* dst = Y + row * COLS;
#pragma unroll
    for (int i = 0; i < V; ++i) dst[lane + i * 64] = __float2bfloat16(v[i] * inv);
}

// ---------------------------------------------------------------------------
// MFMA flash MHSA v4 (verified R7): no online max (scores O(1), exp safe),
// unnormalized P accumulation, single end reduction. Head-separated inputs,
// head-major grid for L2 pinning.
// ---------------------------------------------------------------------------
__global__ __launch_bounds__(256) void mhsa_flash_mfma(
    const bf16* __restrict__ Qb, const bf16* __restrict__ Kb,
    const bf16* __restrict__ VT, bf16* __restrict__ Hout)
{
    constexpr int LD = 72;
    __shared__ __align__(16) ushort Qs[64 * LD];
    __shared__ __align__(16) ushort Ks[64 * LD];
    __shared__ __align__(16) ushort Vt[64 * LD];
    __shared__ __align__(16) ushort Ps[64 * LD];

    const int t = threadIdx.x;
    const int w = t >> 6, lane = t & 63;
    const int l16 = lane & 15, q4 = lane >> 4;
    const int h = blockIdx.x, b = blockIdx.y, qt = blockIdx.z;
    const size_t bh = (size_t)b * 8 + h;
    const ushort* qbase = (const ushort*)Qb + bh * 768 * 64;
    const ushort* kbase = (const ushort*)Kb + bh * 768 * 64;
    const ushort* vbase = (const ushort*)VT + bh * 64 * 768;

    const int r = t >> 2, c0 = (t & 3) * 16;

    {
        const ushort* src = qbase + (size_t)(qt * 64 + r) * 64 + c0;
        *(int4*)&Qs[r * LD + c0]     = *(const int4*)src;
        *(int4*)&Qs[r * LD + c0 + 8] = *(const int4*)(src + 8);
    }

    int4 ka0, ka1, va0, va1;
    {
        const ushort* ks = kbase + (size_t)r * 64 + c0;
        ka0 = *(const int4*)ks; ka1 = *(const int4*)(ks + 8);
        const ushort* vs = vbase + (size_t)r * 768 + c0;
        va0 = *(const int4*)vs; va1 = *(const int4*)(vs + 8);
    }
    __syncthreads();

    short8 qf0 = *(const short8*)&Qs[(w * 16 + l16) * LD + q4 * 8];
    short8 qf1 = *(const short8*)&Qs[(w * 16 + l16) * LD + 32 + q4 * 8];

    float lsum[4] = {0.f, 0.f, 0.f, 0.f};
    f32x4 acc[4] = {};

    for (int kt = 0; kt < 12; ++kt) {
        if (kt) __syncthreads();
        *(int4*)&Ks[r * LD + c0]     = ka0;
        *(int4*)&Ks[r * LD + c0 + 8] = ka1;
        *(int4*)&Vt[r * LD + c0]     = va0;
        *(int4*)&Vt[r * LD + c0 + 8] = va1;
        __syncthreads();

        if (kt < 11) {
            const ushort* ks = kbase + (size_t)((kt + 1) * 64 + r) * 64 + c0;
            ka0 = *(const int4*)ks; ka1 = *(const int4*)(ks + 8);
            const ushort* vs = vbase + (size_t)r * 768 + (kt + 1) * 64 + c0;
            va0 = *(const int4*)vs; va1 = *(const int4*)(vs + 8);
        }

        f32x4 s[4] = {};
#pragma unroll
        for (int nt = 0; nt < 4; ++nt) {
            short8 kf0 = *(const short8*)&Ks[(nt * 16 + l16) * LD + q4 * 8];
            short8 kf1 = *(const short8*)&Ks[(nt * 16 + l16) * LD + 32 + q4 * 8];
            s[nt] = __builtin_amdgcn_mfma_f32_16x16x32_bf16(qf0, kf0, s[nt], 0, 0, 0);
            s[nt] = __builtin_amdgcn_mfma_f32_16x16x32_bf16(qf1, kf1, s[nt], 0, 0, 0);
        }

#pragma unroll
        for (int nt = 0; nt < 4; ++nt) {
#pragma unroll
            for (int e = 0; e < 4; ++e) {
                const float p = __expf(s[nt][e] * 0.125f);
                lsum[e] += p;
                Ps[(w * 16 + q4 * 4 + e) * LD + nt * 16 + l16] = f2b(p);
            }
        }

        short8 pf0 = *(const short8*)&Ps[(w * 16 + l16) * LD + q4 * 8];
        short8 pf1 = *(const short8*)&Ps[(w * 16 + l16) * LD + 32 + q4 * 8];
#pragma unroll
        for (int jt = 0; jt < 4; ++jt) {
            short8 vf0 = *(const short8*)&Vt[(jt * 16 + l16) * LD + q4 * 8];
            short8 vf1 = *(const short8*)&Vt[(jt * 16 + l16) * LD + 32 + q4 * 8];
            acc[jt] = __builtin_amdgcn_mfma_f32_16x16x32_bf16(pf0, vf0, acc[jt], 0, 0, 0);
            acc[jt] = __builtin_amdgcn_mfma_f32_16x16x32_bf16(pf1, vf1, acc[jt], 0, 0, 0);
        }
    }

    const int orow = qt * 64 + w * 16 + q4 * 4;
#pragma unroll
    for (int e = 0; e < 4; ++e) {
        float l = lsum[e];
        l += __shfl_xor(l, 1);
        l += __shfl_xor(l, 2);
        l += __shfl_xor(l, 4);
        l += __shfl_xor(l, 8);
        const float inv = 1.f / l;
        const size_t rbase = ((size_t)b * 768 + orow + e) * 512 + h * 64;
#pragma unroll
        for (int jt = 0; jt < 4; ++jt)
            Hout[rbase + jt * 16 + l16] = __float2bfloat16(acc[jt][e] * inv);
    }
}

// ---------------------------------------------------------------------------
extern "C" void kernel_launch(void* const* d_in, const int* in_sizes, int n_in,
                              void* d_out, int out_size, void* d_ws, size_t ws_size,
                              hipStream_t stream)
{
    (void)in_sizes; (void)n_in; (void)out_size; (void)ws_size;
    const float* x1     = (const float*)d_in[0];
    const float* x2     = (const float*)d_in[1];
    const float* z_b    = (const float*)d_in[2];
    const float* Wqkv_i = (const float*)d_in[3];
    const float* Wqkv_j = (const float*)d_in[4];
    const float* Wqkv_b = (const float*)d_in[5];
    const float* W_f    = (const float*)d_in[6];
    const float* b_f    = (const float*)d_in[7];
    const float* W_m    = (const float*)d_in[8];
    const float* b_m    = (const float*)d_in[9];
    const float* W_QKV  = (const float*)d_in[10];
    const float* W_proj = (const float*)d_in[11];
    const float* b_proj = (const float*)d_in[12];
    float* out = (float*)d_out;

    const float scale = 0.044194173824159216f;   // 512^-0.5

    char* base = (char*)d_ws;
    size_t off = 0;
    auto alloc = [&](size_t bytes) { char* r = base + off; off += (bytes + 255) & ~(size_t)255; return r; };

    char* Rq  = alloc((size_t)3 * 25165824);
    char* R1  = Rq;                 // Kc bf16 | Qb+Kb bf16
    char* R2  = Rq + 25165824;      // v_iT bf16 | VTb bf16
    char* R3  = Rq + 2 * 25165824;  // c_x1 bf16
    char* R4  = alloc(25165824);    // Hout bf16
    bf16* Wt4     = (bf16*)alloc((size_t)3 * 1536 * 512 * 2);  // i, b, qkv
    bf16* Wt_f    = (bf16*)alloc(512 * 1024 * 2);
    bf16* Wt_mp   = (bf16*)alloc((size_t)2 * 512 * 512 * 2);   // m, proj
    bf16* Wj_bf   = (bf16*)alloc(512 * 512 * 2);               // Wqkv_j[:, :512] bf16
    bf16* Gbuf    = (bf16*)alloc(256 * 512 * 2);               // G = k_b @ Wj^T
    bf16* c_zb    = (bf16*)alloc(256 * 512 * 2);
    bf16* qkvb    = (bf16*)alloc(256 * 1536 * 2);
    bf16* aib0    = (bf16*)alloc((size_t)16 * 256 * 512 * 2);
    bf16* Bcat    = (bf16*)alloc((size_t)16 * 512 * 512 * 2);  // [aib0^T | v_b^T]
    float* S      = (float*)alloc((size_t)16 * 256 * 768 * 4);
    bf16* Sb1     = (bf16*)alloc((size_t)16 * 256 * 768 * 2);
    bf16* Sb_cat  = (bf16*)alloc((size_t)16 * 768 * 512 * 2);  // [P2 | P3] K-concat
    bf16* c_cat   = (bf16*)alloc((size_t)12288 * 1024 * 2);
    bf16* hbuf    = (bf16*)alloc((size_t)12288 * 512 * 2);

    bf16* Wt_i = Wt4, *Wt_b = Wt4 + 1536 * 512,
        *Wt_qkv = Wt4 + (size_t)2 * 1536 * 512;
    bf16* Wt_m = Wt_mp, *Wt_proj = Wt_mp + 512 * 512;

    bf16*  Kc   = (bf16*)R1;                 // [16][768][512]
    bf16*  Qb   = (bf16*)R1;                 // [16][8][768][64] (after Kc dead)
    bf16*  Kb   = (bf16*)(R1 + 12582912);
    bf16*  v_iT = (bf16*)R2;                 // [16][512][768]
    bf16*  VTb  = (bf16*)R2;                 // [16][8][64][768] (after v_iT dead)
    bf16*  c_x1 = (bf16*)R3;
    bf16*  Hout = (bf16*)R4;

    // TM=64 plain GEMM launcher; nry>0 = flattened batch-in-y grid;
    // bd = B-direct (L2-hot <=1MB B panels only)
    auto G64 = [&](const bf16* A, const bf16* B, void* C, bool outBf,
                   int M, int N, int K, int lda, int ldb, int ldc,
                   long sA, long sB, long sC, int batch, float alpha,
                   const float* bias, bool bd) {
        int nry = M / 64;
        dim3 grid(N / 128, (batch > 1) ? batch * nry : nry, 1);
        if (batch == 1) nry = 0;
        if (outBf) {
            if (bd) gemm_bf16<bf16, 0, 64, true><<<grid, 256, 0, stream>>>(A, B, (bf16*)C, K, lda, ldb, ldc, sA, sB, sC, alpha, bias, 0, 0, 0, 0, nullptr, nullptr, nry);
            else    gemm_bf16<bf16, 0, 64, false><<<grid, 256, 0, stream>>>(A, B, (bf16*)C, K, lda, ldb, ldc, sA, sB, sC, alpha, bias, 0, 0, 0, 0, nullptr, nullptr, nry);
        } else {
            if (bd) gemm_bf16<float, 0, 64, true><<<grid, 256, 0, stream>>>(A, B, (float*)C, K, lda, ldb, ldc, sA, sB, sC, alpha, bias, 0, 0, 0, 0, nullptr, nullptr, nry);
            else    gemm_bf16<float, 0, 64, false><<<grid, 256, 0, stream>>>(A, B, (float*)C, K, lda, ldb, ldc, sA, sB, sC, alpha, bias, 0, 0, 0, 0, nullptr, nullptr, nry);
        }
    };

    // ---- stage 0: one cast dispatch + ONE merged transpose dispatch ----
    k_cast3<<<dim3(3072, 1, 4), 256, 0, stream>>>(x1, x2, z_b, Wqkv_j,
                                                  c_x1, c_cat + 512, c_zb, Wj_bf);
    k_transpose_all<<<dim3(24, 16, 6), 256, 0, stream>>>(
        Wqkv_i, Wqkv_b, W_QKV, W_f, W_m, W_proj, Wt4, Wt_f, Wt_mp);

    // 1. qkvb = (0.2 zb) @ Wqkv_b  [256,1536] bf16; v-section also writes
    //    v_b^T replicated into Bcat[:, :, 256:512]  [EPI 8 fold]
    gemm_bf16<bf16, 8, 64><<<dim3(12, 4, 1), 256, 0, stream>>>(
        c_zb, Wt_b, qkvb, 512, 512, 512, 1536, 0, 0, 0,
        1.f, nullptr, 0, 0, 0, 512L * 512, nullptr, Bcat, 0);
    // 1b. G = k_b @ Wj^T  [256,512] bf16  (S3 = x2@G^T by associativity) [BD]
    G64(qkvb + 512, Wj_bf, Gbuf, true, 256, 512, 512, 1536, 512, 512, 0, 0, 0, 1, 1.f, nullptr, true);
    // 2. [k_i|v_i] = x1 @ Wqkv_i[:,512:]  -> Kc compact + v_iT transposed
    gemm_bf16<bf16, 5, 128><<<dim3(8, 96, 1), 256, 0, stream>>>(
        c_x1, Wt_i + 512 * 512, Kc, 512, 512, 512, 512, 0, 0, 0,
        1.f, nullptr, 0, 0, 0, 0, nullptr, v_iT, 0);
    // 4. S1 = scale * q_b @ k_i^T   [16][256,768] f32   (flattened y=64)
    G64(qkvb, Kc, S, false, 256, 768, 512, 1536, 512, 768, 0, 768L * 512, 256L * 768, 16, scale, nullptr, false);
    softmax_wave<768, 0><<<1024, 256, 0, stream>>>(S, Sb1);
    // 5. aib0 = softmax1 @ v_i  -> aib0 + Bcat[:, :, 0:256]  (flat y=64)
    gemm_bf16<bf16, 6, 64><<<dim3(4, 64, 1), 256, 0, stream>>>(
        Sb1, v_iT, aib0, 768, 768, 768, 512, 256L * 768, 512L * 768, 256L * 512,
        1.f, nullptr, 0, 0, 512, 512L * 512, nullptr, Bcat, 4);
    // 6+8+sm. fused: Sb_cat = [sm(scale*x1@aib0^T) | sm(scale*x2@G^T)]
    gemm_sm<<<dim3(1, 192, 2), 256, 0, stream>>>(c_x1, aib0, c_cat + 512, Gbuf,
                                                 Sb_cat, scale);
    // 7+9+10. a_ij = 0.5 * [P2|P3] @ [aib0; v_b]  -> c_cat[:, :512]  [BD]
    G64(Sb_cat, Bcat, c_cat, true, 768, 512, 512, 512, 512, 1024,
        768L * 512, 512L * 512, 768L * 1024, 16, 0.5f, nullptr, true);
    // 11+12. fused gate: hbuf = relu(x1 + (a_ij@W_m + b_m)*sigmoid([a_ij|x2]@W_f + b_f))
    gemm_gate<<<dim3(4, 192), 256, 0, stream>>>(c_cat, Wt_f, Wt_m, hbuf, b_f, b_m, c_x1);
    // 13. QKV = h @ W_QKV -> head-separated Qb/Kb/VTb      [fused scatter]
    gemm_bf16<bf16, 4, 128><<<dim3(12, 96, 1), 256, 0, stream>>>(
        hbuf, Wt_qkv, Qb, 512, 512, 512, 0, 0, 0, 0,
        1.f, nullptr, 0, 0, 0, 0, Kb, VTb, 0);
    // 14. MFMA flash MHSA -> Hout bf16
    mhsa_flash_mfma<<<dim3(8, 16, 12), 256, 0, stream>>>(Qb, Kb, VTb, Hout);
    // 15. out = Hout @ W_proj + b_proj          f32   [BD]
    G64(Hout, Wt_proj, out, false, 12288, 512, 512, 512, 512, 512, 0, 0, 0, 1, 1.f, b_proj, true);
}

// Round 11
// 380.525 us; speedup vs baseline: 1.1010x; 1.1010x over previous
//
#include <hip/hip_runtime.h>
#include <hip/hip_bf16.h>

typedef __attribute__((ext_vector_type(8))) short short8;
typedef __attribute__((ext_vector_type(4))) float f32x4;
typedef __hip_bfloat16 bf16;
typedef unsigned short ushort;

__device__ __forceinline__ ushort f2b(float v) {
    bf16 h = __float2bfloat16(v);
    return *reinterpret_cast<ushort*>(&h);
}
__device__ __forceinline__ float b2f(ushort u) {
    return __uint_as_float((unsigned)u << 16);
}

#define GLD16(lds, gp) __builtin_amdgcn_global_load_lds( \
    (const __attribute__((address_space(1))) void*)(gp), \
    (__attribute__((address_space(3))) void*)(lds), 16, 0, 0)

// XCD-affinity swizzle (R3-verified: gate FETCH 64.6->37MB). Bijective when
// gridDim.y%8==0 and z==1; otherwise identity. Perf heuristic only.
__device__ __forceinline__ void xcd_swizzle(int& bx, int& by) {
    if (gridDim.z == 1 && (gridDim.y & 7) == 0) {
        const int id = bx + gridDim.x * by;
        const int xcd = id & 7, slot = id >> 3;
        by = xcd * (gridDim.y >> 3) + slot / gridDim.x;
        bx = slot - (slot / gridDim.x) * gridDim.x;
    }
}

// ---------------------------------------------------------------------------
// bf16 MFMA GEMM: C = alpha * A @ B^T (+ bias) with fused epilogues.
// R12 staged core (R4 proved LDS-free is 2x WORSE: direct fragments
// quadruple L2 line-requests; R10 re-proved it for B-only direct - loads
// issued inside the compute phase expose their latency serially).
// Coalesced row-major[r][32] chunk-rotation LDS layout (bank-conflict 0).
// 2-phase double-buffer, one __syncthreads per phase, all loads issued a
// full phase ahead of use.
// TM=64: BK=64 phases (2 planes/buffer, LDS 48KB, 3 blk/CU).
// TM=128: BK=32 (BK=64 would need 64KB -> 2 blk/CU, m132 regression).
// EPI 0: plain.
// EPI 4: QKV head-scatter: C=Qb, px=Kb, py=VT   [b][h][n][hd] / [b][h][hd][n]
// EPI 5: KV split: C=Kc [b][n][512], py=v_iT [b][hd][768]
// EPI 6: dual write: C normal + py transposed (eld=transposed ld, sE=batch str)
// EPI 7: batched-pair: z<16 uses (A,lda,sA,B,ldb,sB); z>=16 uses
//        (px,lda2,sA2, py,eld,sB=0)  [z>=16 = x2 @ G^T]
// ---------------------------------------------------------------------------
template<typename OutT, int EPI, int TM>
__global__ __launch_bounds__(256) void gemm_bf16(
    const bf16* __restrict__ A, const bf16* __restrict__ B, OutT* __restrict__ C,
    int K, int lda, int ldb, int ldc, long sA, long sB, long sC,
    float alpha, const float* __restrict__ bias,
    int lda2, long sA2, int eld, long sE,
    bf16* __restrict__ px, bf16* __restrict__ py)
{
    constexpr int RT = TM / 32;              // row MFMA-tiles per wave
    constexpr int PLA = TM * 32;             // halfwords per 32-k A plane
    constexpr int PLB = 128 * 32;
    constexpr int NP = (TM == 64) ? 4 : 2;   // planes total (2 bufs x {2,1})
    __shared__ __align__(16) bf16 As[NP * PLA];
    __shared__ __align__(16) bf16 Bs[NP * PLB];

    const int t = threadIdx.x;
    const int w = t >> 6, lane = t & 63;
    const int wr = w >> 1, wc = w & 1;
    const int lr = lane & 15, kc4 = lane >> 4;
    const int qr = lane >> 2;                              // row within 16-row slice
    const int kcr = ((lane & 3) - ((lane >> 3) & 3)) & 3;  // rotated global k-chunk
    int bx = blockIdx.x, by = blockIdx.y;
    xcd_swizzle(bx, by);
    const int row0 = by * TM, col0 = bx * 128;
    const int bz = blockIdx.z;

    const bf16* Asel = A; const bf16* Bsel = B;
    int abz = bz; long sBe = sB, sAe = sA; int ldbe = ldb, ldae = lda;
    if constexpr (EPI == 7) {
        if (bz >= 16) {
            Asel = (const bf16*)px; Bsel = (const bf16*)py;
            abz = bz - 16; sBe = 0; ldbe = eld; ldae = lda2; sAe = sA2;
        }
    }
    const bf16* Ab = Asel + (size_t)abz * sAe + (size_t)row0 * ldae;
    const bf16* Bb = Bsel + (size_t)abz * sBe + (size_t)col0 * ldbe;

    // staging: each GLD16 covers 16 rows x 64B (4 lanes/row, coalesced)
    const bf16* ga0; const bf16* ga1 = nullptr;
    if constexpr (TM == 64) {
        ga0 = Ab + (size_t)(w * 16 + qr) * ldae + kcr * 8;
    } else {
        ga0 = Ab + (size_t)(w * 32 + qr) * ldae + kcr * 8;
        ga1 = Ab + (size_t)(w * 32 + 16 + qr) * ldae + kcr * 8;
    }
    const bf16* gb0 = Bb + (size_t)(w * 32 + qr) * ldbe + kcr * 8;
    const bf16* gb1 = Bb + (size_t)(w * 32 + 16 + qr) * ldbe + kcr * 8;
    bf16* lA0; bf16* lA1 = nullptr;
    if constexpr (TM == 64) { lA0 = &As[w * 512]; }
    else                    { lA0 = &As[w * 1024]; lA1 = &As[w * 1024 + 512]; }
    bf16* lB0 = &Bs[w * 1024];
    bf16* lB1 = &Bs[w * 1024 + 512];

    f32x4 acc[RT][4] = {};

    const int cSw = ((kc4 + ((lr >> 1) & 3)) & 3) * 8;     // swizzled chunk offset
    const bf16* ApBase = &As[(wr * (TM / 2) + lr) * 32 + cSw];
    const bf16* BpBase = &Bs[(wc * 64 + lr) * 32 + cSw];

    auto stageP = [&](int plane, int ko) {
        GLD16(lA0 + plane * PLA, ga0 + ko);
        if constexpr (TM == 128) GLD16(lA1 + plane * PLA, ga1 + ko);
        GLD16(lB0 + plane * PLB, gb0 + ko);
        GLD16(lB1 + plane * PLB, gb1 + ko);
    };
    auto compP = [&](int plane) {
        const bf16* Ap = ApBase + plane * PLA;
        const bf16* Bp = BpBase + plane * PLB;
        short8 af[RT], bfr[4];
#pragma unroll
        for (int i = 0; i < RT; ++i) af[i]  = *(const short8*)(Ap + i * 512);
#pragma unroll
        for (int j = 0; j < 4; ++j) bfr[j] = *(const short8*)(Bp + j * 512);
#pragma unroll
        for (int i = 0; i < RT; ++i)
#pragma unroll
            for (int j = 0; j < 4; ++j)
                acc[i][j] = __builtin_amdgcn_mfma_f32_16x16x32_bf16(af[i], bfr[j], acc[i][j], 0, 0, 0);
    };

    if constexpr (TM == 64) {
        stageP(0, 0); stageP(1, 32);        // prologue: buffer 0, planes 0..1
        int buf = 0;
        for (int k0 = 0; k0 < K; k0 += 64) {   // K % 64 == 0 at all call sites
            __syncthreads();                   // cur buf staged; other buf free
            if (k0 + 64 < K) {
                stageP((buf ^ 1) * 2,     k0 + 64);
                stageP((buf ^ 1) * 2 + 1, k0 + 96);
            }
            compP(buf * 2); compP(buf * 2 + 1);
            buf ^= 1;
        }
    } else {
        stageP(0, 0);
        int buf = 0;
        for (int k0 = 0; k0 < K; k0 += 32) {
            __syncthreads();
            if (k0 + 32 < K) stageP(buf ^ 1, k0 + 32);
            compP(buf);
            buf ^= 1;
        }
    }

    if constexpr (EPI == 4) {
        const int sec = bx >> 2;                    // 0=q 1=k 2=v
        const int h0 = (bx & 3) * 2;
        const int b  = by / 6;
        const int n0 = (by % 6) * TM;
        bf16* dq = (bf16*)C;
#pragma unroll
        for (int j = 0; j < 4; ++j) {
            const int col = wc * 64 + j * 16 + lr;
            const int h = h0 + (col >> 6), hd = col & 63;
            const size_t bh = (size_t)b * 8 + h;
#pragma unroll
            for (int i = 0; i < RT; ++i) {
                const int n = n0 + wr * (TM / 2) + i * 16 + kc4 * 4;
                if (sec == 2) {
                    __align__(8) ushort o[4];
#pragma unroll
                    for (int r = 0; r < 4; ++r) o[r] = f2b(acc[i][j][r]);
                    *(int2*)&py[(bh * 64 + hd) * 768 + n] = *(const int2*)o;
                } else {
                    bf16* d = (sec == 0) ? dq : px;
#pragma unroll
                    for (int r = 0; r < 4; ++r)
                        d[(bh * 768 + n + r) * 64 + hd] = __float2bfloat16(acc[i][j][r]);
                }
            }
        }
        return;
    } else if constexpr (EPI == 5) {
        const int b  = by / 6;
        const int n0 = (by % 6) * TM;
#pragma unroll
        for (int j = 0; j < 4; ++j) {
            const int col = col0 + wc * 64 + j * 16 + lr;
#pragma unroll
            for (int i = 0; i < RT; ++i) {
                const int n = n0 + wr * (TM / 2) + i * 16 + kc4 * 4;
                if (col < 512) {
#pragma unroll
                    for (int r = 0; r < 4; ++r)
                        ((bf16*)C)[((size_t)b * 768 + n + r) * 512 + col] = __float2bfloat16(acc[i][j][r]);
                } else {
                    __align__(8) ushort o[4];
#pragma unroll
                    for (int r = 0; r < 4; ++r) o[r] = f2b(acc[i][j][r]);
                    *(int2*)&py[((size_t)b * 512 + (col - 512)) * 768 + n] = *(const int2*)o;
                }
            }
        }
        return;
    }

    OutT* Cb = C + (size_t)bz * sC;
#pragma unroll
    for (int j = 0; j < 4; ++j) {
        const int col = col0 + wc * 64 + j * 16 + lr;
        const float bv = bias ? bias[col] : 0.f;
#pragma unroll
        for (int i = 0; i < RT; ++i) {
            const int rb = row0 + wr * (TM / 2) + i * 16 + kc4 * 4;
            if constexpr (EPI == 6) {
                __align__(8) ushort o[4];
#pragma unroll
                for (int r = 0; r < 4; ++r) {
                    o[r] = f2b(alpha * acc[i][j][r]);
                    Cb[(size_t)(rb + r) * ldc + col] = __float2bfloat16(alpha * acc[i][j][r]);
                }
                *(int2*)&py[(size_t)bz * sE + (size_t)col * eld + rb] = *(const int2*)o;
            } else {
#pragma unroll
                for (int r = 0; r < 4; ++r) {
                    const int row = rb + r;
                    float v = alpha * acc[i][j][r] + bv;
                    if constexpr (sizeof(OutT) == 2)
                        Cb[(size_t)row * ldc + col] = __float2bfloat16(v);
                    else
                        Cb[(size_t)row * ldc + col] = v;
                }
            }
        }
    }
}

// ---------------------------------------------------------------------------
// Fused gate GEMM (steps 11+12), grid (4,192) = 768 (3 blk/CU).
// R9 shared-A form (best measured) + XCD swizzle. Per 32-k phase: stage
// A(1)+F(2)+M(2 while k<512) GLD16/wave; compute 8 F-MFMA (+8 M-MFMA
// sharing the A fragments). LDS 40KB.
// ---------------------------------------------------------------------------
__global__ __launch_bounds__(256) void gemm_gate(
    const bf16* __restrict__ A, const bf16* __restrict__ Bf,
    const bf16* __restrict__ Bm, bf16* __restrict__ Cout,
    const float* __restrict__ bias_f, const float* __restrict__ bias_m,
    const float* __restrict__ x1)
{
    constexpr int AHW = 64 * 32;
    constexpr int BHW = 128 * 32;
    __shared__ __align__(16) bf16 As[2 * AHW];
    __shared__ __align__(16) bf16 FsS[2 * BHW];
    __shared__ __align__(16) bf16 MsS[2 * BHW];

    const int t = threadIdx.x;
    const int w = t >> 6, lane = t & 63;
    const int wr = w >> 1, wc = w & 1;
    const int lr = lane & 15, kc4 = lane >> 4;
    const int qr = lane >> 2;
    const int kcr = ((lane & 3) - ((lane >> 3) & 3)) & 3;
    int bx = blockIdx.x, by = blockIdx.y;
    xcd_swizzle(bx, by);
    const int row0 = by * 64, col0 = bx * 128;

    const bf16* ga0 = A  + (size_t)(row0 + w * 16 + qr) * 1024 + kcr * 8;
    const bf16* gf0 = Bf + (size_t)(col0 + w * 32 + qr) * 1024 + kcr * 8;
    const bf16* gf1 = Bf + (size_t)(col0 + w * 32 + 16 + qr) * 1024 + kcr * 8;
    const bf16* gm0 = Bm + (size_t)(col0 + w * 32 + qr) * 512 + kcr * 8;
    const bf16* gm1 = Bm + (size_t)(col0 + w * 32 + 16 + qr) * 512 + kcr * 8;
    bf16* lA0 = &As[w * 512];
    bf16* lF0 = &FsS[w * 1024]; bf16* lF1 = &FsS[w * 1024 + 512];
    bf16* lM0 = &MsS[w * 1024]; bf16* lM1 = &MsS[w * 1024 + 512];

    f32x4 acc1[2][4] = {};   // fg
    f32x4 acc2[2][4] = {};   // hm

    const int cSw = ((kc4 + ((lr >> 1) & 3)) & 3) * 8;
    const bf16* ApBase = &As[(wr * 32 + lr) * 32 + cSw];
    const bf16* FpBase = &FsS[(wc * 64 + lr) * 32 + cSw];
    const bf16* MpBase = &MsS[(wc * 64 + lr) * 32 + cSw];

    // prologue: stage k=0 into buffer 0
    GLD16(lA0, ga0);
    GLD16(lF0, gf0); GLD16(lF1, gf1);
    GLD16(lM0, gm0); GLD16(lM1, gm1);

    auto step = [&](int kk, int rd, int st) {
        __syncthreads();
        const int kn = kk + 32;
        if (kn < 1024) {
            GLD16(lA0 + st * AHW, ga0 + kn);
            GLD16(lF0 + st * BHW, gf0 + kn);
            GLD16(lF1 + st * BHW, gf1 + kn);
            if (kn < 512) {
                GLD16(lM0 + st * BHW, gm0 + kn);
                GLD16(lM1 + st * BHW, gm1 + kn);
            }
        }
        const bf16* Ap = ApBase + rd * AHW;
        const bf16* Fp = FpBase + rd * BHW;
        short8 af[2], ff[4];
#pragma unroll
        for (int i = 0; i < 2; ++i) af[i] = *(const short8*)(Ap + i * 512);
#pragma unroll
        for (int j = 0; j < 4; ++j) ff[j] = *(const short8*)(Fp + j * 512);
#pragma unroll
        for (int i = 0; i < 2; ++i)
#pragma unroll
            for (int j = 0; j < 4; ++j)
                acc1[i][j] = __builtin_amdgcn_mfma_f32_16x16x32_bf16(af[i], ff[j], acc1[i][j], 0, 0, 0);
        if (kk < 512) {
            const bf16* Mp = MpBase + rd * BHW;
            short8 mf[4];
#pragma unroll
            for (int j = 0; j < 4; ++j) mf[j] = *(const short8*)(Mp + j * 512);
#pragma unroll
            for (int i = 0; i < 2; ++i)
#pragma unroll
                for (int j = 0; j < 4; ++j)
                    acc2[i][j] = __builtin_amdgcn_mfma_f32_16x16x32_bf16(af[i], mf[j], acc2[i][j], 0, 0, 0);
        }
    };

    for (int k0 = 0; k0 < 1024; k0 += 64) {
        step(k0, 0, 1);
        step(k0 + 32, 1, 0);
    }

#pragma unroll
    for (int j = 0; j < 4; ++j) {
        const int col = col0 + wc * 64 + j * 16 + lr;
        const float bvf = bias_f[col], bvm = bias_m[col];
#pragma unroll
        for (int i = 0; i < 2; ++i) {
            const int rb = row0 + wr * 32 + i * 16 + kc4 * 4;
#pragma unroll
            for (int r = 0; r < 4; ++r) {
                const int row = rb + r;
                const float sig = 1.f / (1.f + __expf(-(acc1[i][j][r] + bvf)));
                const float rr = x1[(size_t)row * 512 + col] + (acc2[i][j][r] + bvm) * sig;
                Cout[(size_t)row * 512 + col] = __float2bfloat16(rr > 0.f ? rr : 0.f);
            }
        }
    }
}

// ---------------------------------------------------------------------------
// Transpose + cast to bf16: src [R,C] -> dst [C,R] bf16. Multi-source via z.
// rep/repStride: replicate the transposed output (for broadcast B panels).
// ---------------------------------------------------------------------------
template<typename TI, int NSRC>
__global__ __launch_bounds__(256) void k_transpose(
    const TI* __restrict__ s0, const TI* __restrict__ s1,
    const TI* __restrict__ s2, const TI* __restrict__ s3,
    bf16* __restrict__ dst, int src_ld, int dst_ld, long sSrc, long sDst,
    int rep, long repStride)
{
    __shared__ float tile[64][65];
    const int t = threadIdx.x;
    const int c0 = blockIdx.x * 64, r0 = blockIdx.y * 64;
    const int z = blockIdx.z;
    const TI* src = s0;
    if (NSRC > 1) src = (z == 0) ? s0 : (z == 1) ? s1 : (z == 2) ? s2 : s3;
    {
        const int r = t >> 2, cq = (t & 3) * 16;
        const TI* sp = src + (size_t)z * sSrc + (size_t)(r0 + r) * src_ld + c0 + cq;
        if constexpr (sizeof(TI) == 4) {
#pragma unroll
            for (int u = 0; u < 16; u += 4) {
                float4 v = *(const float4*)((const float*)sp + u);
                tile[r][cq + u]     = v.x; tile[r][cq + u + 1] = v.y;
                tile[r][cq + u + 2] = v.z; tile[r][cq + u + 3] = v.w;
            }
        } else {
            const ushort* up = (const ushort*)sp;
            union { short8 v; ushort u[8]; } p0, p1;
            p0.v = *(const short8*)up; p1.v = *(const short8*)(up + 8);
#pragma unroll
            for (int u = 0; u < 8; ++u) {
                tile[r][cq + u]     = b2f(p0.u[u]);
                tile[r][cq + 8 + u] = b2f(p1.u[u]);
            }
        }
    }
    __syncthreads();
    const int c = t >> 2, rq = (t & 3) * 16;
    __align__(16) ushort ob[16];
#pragma unroll
    for (int u = 0; u < 16; ++u) ob[u] = f2b(tile[rq + u][c]);
    for (int rp = 0; rp < rep; ++rp) {
        bf16* dp = dst + (size_t)rp * repStride + (size_t)z * sDst + (size_t)(c0 + c) * dst_ld + r0 + rq;
        *(int4*)dp       = *(const int4*)&ob[0];
        *(int4*)(dp + 8) = *(const int4*)&ob[8];
    }
}

// input casts in one dispatch (z selects job). z==3: strided read of
// Wqkv_j[:, :512] (f32 ld 1536) -> Wj_bf [512][512] bf16 (for the G trick).
__global__ __launch_bounds__(256) void k_cast3(const float* __restrict__ x1,
    const float* __restrict__ x2, const float* __restrict__ zb,
    const float* __restrict__ wj,
    bf16* __restrict__ d1, bf16* __restrict__ d2, bf16* __restrict__ d3,
    bf16* __restrict__ d4)
{
    const int z = blockIdx.z;
    const float* src; bf16* dst; int ld; float scale; int n;
    if (z == 0)      { src = x1; dst = d1; ld = 512;  scale = 1.f;  n = 6291456; }
    else if (z == 1) { src = x2; dst = d2; ld = 1024; scale = 1.f;  n = 6291456; }
    else if (z == 2) { src = zb; dst = d3; ld = 512;  scale = 0.2f; n = 131072;  }
    else             { src = wj; dst = d4; ld = 512;  scale = 1.f;  n = 262144;  }
    int i = (blockIdx.x * 256 + threadIdx.x) * 8;
    if (i >= n) return;
    int si = i;
    if (z == 3) si = (i >> 9) * 1536 + (i & 511);
    float4 a = *(const float4*)(src + si), b = *(const float4*)(src + si + 4);
    __align__(16) ushort o[8];
    o[0] = f2b(a.x * scale); o[1] = f2b(a.y * scale); o[2] = f2b(a.z * scale); o[3] = f2b(a.w * scale);
    o[4] = f2b(b.x * scale); o[5] = f2b(b.y * scale); o[6] = f2b(b.z * scale); o[7] = f2b(b.w * scale);
    int row = i >> 9, col = i & 511;
    *(int4*)(dst + (size_t)row * ld + col) = *(const int4*)o;
}

// ---------------------------------------------------------------------------
// Wave-per-row softmax f32 -> bf16. 4 rows/block (one per wave), no barriers.
// MODE 0: dst = Y + row*COLS.
// MODE 1 (merged S2/S3, COLS=256): row = z*768+m, z in [0,32);
//   dst = Y + ((z&15)*768+m)*512 + (z>>4)*256   (K-concat layout).
// ---------------------------------------------------------------------------
template<int COLS, int MODE>
__global__ __launch_bounds__(256) void softmax_wave(const float* __restrict__ X,
                                                    bf16* __restrict__ Y)
{
    const int wv = threadIdx.x >> 6, lane = threadIdx.x & 63;
    const long row = (long)blockIdx.x * 4 + wv;
    const float* src = X + row * COLS;
    constexpr int V = COLS / 64;
    float v[V];
#pragma unroll
    for (int i = 0; i < V; ++i) v[i] = src[lane + i * 64];
    float m = v[0];
#pragma unroll
    for (int i = 1; i < V; ++i) m = fmaxf(m, v[i]);
#pragma unroll
    for (int o = 32; o; o >>= 1) m = fmaxf(m, __shfl_xor(m, o));
    float s = 0.f;
#pragma unroll
    for (int i = 0; i < V; ++i) { v[i] = __expf(v[i] - m); s += v[i]; }
#pragma unroll
    for (int o = 32; o; o >>= 1) s += __shfl_xor(s, o);
    const float inv = 1.f / s;
    bf16* dst;
    if constexpr (MODE == 0) {
        dst = Y + row * COLS;
    } else {
        const int z = (int)(row / 768), mm = (int)(row % 768);
        dst = Y + ((size_t)(z & 15) * 768 + mm) * 512 + (z >> 4) * 256;
    }
#pragma unroll
    for (int i = 0; i < V; ++i) dst[lane + i * 64] = __float2bfloat16(v[i] * inv);
}

// ---------------------------------------------------------------------------
// MFMA flash MHSA v4 (verified R7): no online max (scores O(1), exp safe),
// unnormalized P accumulation, single end reduction. Head-separated inputs,
// head-major grid for L2 pinning.
// ---------------------------------------------------------------------------
__global__ __launch_bounds__(256) void mhsa_flash_mfma(
    const bf16* __restrict__ Qb, const bf16* __restrict__ Kb,
    const bf16* __restrict__ VT, bf16* __restrict__ Hout)
{
    constexpr int LD = 72;
    __shared__ __align__(16) ushort Qs[64 * LD];
    __shared__ __align__(16) ushort Ks[64 * LD];
    __shared__ __align__(16) ushort Vt[64 * LD];
    __shared__ __align__(16) ushort Ps[64 * LD];

    const int t = threadIdx.x;
    const int w = t >> 6, lane = t & 63;
    const int l16 = lane & 15, q4 = lane >> 4;
    const int h = blockIdx.x, b = blockIdx.y, qt = blockIdx.z;
    const size_t bh = (size_t)b * 8 + h;
    const ushort* qbase = (const ushort*)Qb + bh * 768 * 64;
    const ushort* kbase = (const ushort*)Kb + bh * 768 * 64;
    const ushort* vbase = (const ushort*)VT + bh * 64 * 768;

    const int r = t >> 2, c0 = (t & 3) * 16;

    {
        const ushort* src = qbase + (size_t)(qt * 64 + r) * 64 + c0;
        *(int4*)&Qs[r * LD + c0]     = *(const int4*)src;
        *(int4*)&Qs[r * LD + c0 + 8] = *(const int4*)(src + 8);
    }

    int4 ka0, ka1, va0, va1;
    {
        const ushort* ks = kbase + (size_t)r * 64 + c0;
        ka0 = *(const int4*)ks; ka1 = *(const int4*)(ks + 8);
        const ushort* vs = vbase + (size_t)r * 768 + c0;
        va0 = *(const int4*)vs; va1 = *(const int4*)(vs + 8);
    }
    __syncthreads();

    short8 qf0 = *(const short8*)&Qs[(w * 16 + l16) * LD + q4 * 8];
    short8 qf1 = *(const short8*)&Qs[(w * 16 + l16) * LD + 32 + q4 * 8];

    float lsum[4] = {0.f, 0.f, 0.f, 0.f};
    f32x4 acc[4] = {};

    for (int kt = 0; kt < 12; ++kt) {
        if (kt) __syncthreads();
        *(int4*)&Ks[r * LD + c0]     = ka0;
        *(int4*)&Ks[r * LD + c0 + 8] = ka1;
        *(int4*)&Vt[r * LD + c0]     = va0;
        *(int4*)&Vt[r * LD + c0 + 8] = va1;
        __syncthreads();

        if (kt < 11) {
            const ushort* ks = kbase + (size_t)((kt + 1) * 64 + r) * 64 + c0;
            ka0 = *(const int4*)ks; ka1 = *(const int4*)(ks + 8);
            const ushort* vs = vbase + (size_t)r * 768 + (kt + 1) * 64 + c0;
            va0 = *(const int4*)vs; va1 = *(const int4*)(vs + 8);
        }

        f32x4 s[4] = {};
#pragma unroll
        for (int nt = 0; nt < 4; ++nt) {
            short8 kf0 = *(const short8*)&Ks[(nt * 16 + l16) * LD + q4 * 8];
            short8 kf1 = *(const short8*)&Ks[(nt * 16 + l16) * LD + 32 + q4 * 8];
            s[nt] = __builtin_amdgcn_mfma_f32_16x16x32_bf16(qf0, kf0, s[nt], 0, 0, 0);
            s[nt] = __builtin_amdgcn_mfma_f32_16x16x32_bf16(qf1, kf1, s[nt], 0, 0, 0);
        }

#pragma unroll
        for (int nt = 0; nt < 4; ++nt) {
#pragma unroll
            for (int e = 0; e < 4; ++e) {
                const float p = __expf(s[nt][e] * 0.125f);
                lsum[e] += p;
                Ps[(w * 16 + q4 * 4 + e) * LD + nt * 16 + l16] = f2b(p);
            }
        }

        short8 pf0 = *(const short8*)&Ps[(w * 16 + l16) * LD + q4 * 8];
        short8 pf1 = *(const short8*)&Ps[(w * 16 + l16) * LD + 32 + q4 * 8];
#pragma unroll
        for (int jt = 0; jt < 4; ++jt) {
            short8 vf0 = *(const short8*)&Vt[(jt * 16 + l16) * LD + q4 * 8];
            short8 vf1 = *(const short8*)&Vt[(jt * 16 + l16) * LD + 32 + q4 * 8];
            acc[jt] = __builtin_amdgcn_mfma_f32_16x16x32_bf16(pf0, vf0, acc[jt], 0, 0, 0);
            acc[jt] = __builtin_amdgcn_mfma_f32_16x16x32_bf16(pf1, vf1, acc[jt], 0, 0, 0);
        }
    }

    const int orow = qt * 64 + w * 16 + q4 * 4;
#pragma unroll
    for (int e = 0; e < 4; ++e) {
        float l = lsum[e];
        l += __shfl_xor(l, 1);
        l += __shfl_xor(l, 2);
        l += __shfl_xor(l, 4);
        l += __shfl_xor(l, 8);
        const float inv = 1.f / l;
        const size_t rbase = ((size_t)b * 768 + orow + e) * 512 + h * 64;
#pragma unroll
        for (int jt = 0; jt < 4; ++jt)
            Hout[rbase + jt * 16 + l16] = __float2bfloat16(acc[jt][e] * inv);
    }
}

// ---------------------------------------------------------------------------
extern "C" void kernel_launch(void* const* d_in, const int* in_sizes, int n_in,
                              void* d_out, int out_size, void* d_ws, size_t ws_size,
                              hipStream_t stream)
{
    (void)in_sizes; (void)n_in; (void)out_size; (void)ws_size;
    const float* x1     = (const float*)d_in[0];
    const float* x2     = (const float*)d_in[1];
    const float* z_b    = (const float*)d_in[2];
    const float* Wqkv_i = (const float*)d_in[3];
    const float* Wqkv_j = (const float*)d_in[4];
    const float* Wqkv_b = (const float*)d_in[5];
    const float* W_f    = (const float*)d_in[6];
    const float* b_f    = (const float*)d_in[7];
    const float* W_m    = (const float*)d_in[8];
    const float* b_m    = (const float*)d_in[9];
    const float* W_QKV  = (const float*)d_in[10];
    const float* W_proj = (const float*)d_in[11];
    const float* b_proj = (const float*)d_in[12];
    float* out = (float*)d_out;

    const float scale = 0.044194173824159216f;   // 512^-0.5

    char* base = (char*)d_ws;
    size_t off = 0;
    auto alloc = [&](size_t bytes) { char* r = base + off; off += (bytes + 255) & ~(size_t)255; return r; };

    char* Rq  = alloc((size_t)3 * 25165824);
    char* R1  = Rq;                 // Kc bf16 | Qb+Kb bf16
    char* R2  = Rq + 25165824;      // v_iT bf16 | VTb bf16
    char* R3  = Rq + 2 * 25165824;  // c_x1 bf16
    char* R4  = alloc(25165824);    // Hout bf16
    bf16* Wt4     = (bf16*)alloc((size_t)3 * 1536 * 512 * 2);  // i, b, qkv
    bf16* Wt_f    = (bf16*)alloc(512 * 1024 * 2);
    bf16* Wt_mp   = (bf16*)alloc((size_t)2 * 512 * 512 * 2);   // m, proj
    bf16* Wj_bf   = (bf16*)alloc(512 * 512 * 2);               // Wqkv_j[:, :512] bf16
    bf16* Gbuf    = (bf16*)alloc(256 * 512 * 2);               // G = k_b @ Wj^T
    bf16* c_zb    = (bf16*)alloc(256 * 512 * 2);
    bf16* qkvb    = (bf16*)alloc(256 * 1536 * 2);
    bf16* aib0    = (bf16*)alloc((size_t)16 * 256 * 512 * 2);
    bf16* Bcat    = (bf16*)alloc((size_t)16 * 512 * 512 * 2);  // [aib0^T | v_b^T]
    float* S      = (float*)alloc((size_t)32 * 768 * 256 * 4);
    bf16* Sb1     = (bf16*)alloc((size_t)16 * 256 * 768 * 2);
    bf16* Sb_cat  = (bf16*)alloc((size_t)16 * 768 * 512 * 2);  // [P2 | P3] K-concat
    bf16* c_cat   = (bf16*)alloc((size_t)12288 * 1024 * 2);
    bf16* hbuf    = (bf16*)alloc((size_t)12288 * 512 * 2);

    bf16* Wt_i = Wt4, *Wt_b = Wt4 + 1536 * 512,
        *Wt_qkv = Wt4 + (size_t)2 * 1536 * 512;
    bf16* Wt_m = Wt_mp, *Wt_proj = Wt_mp + 512 * 512;

    bf16*  Kc   = (bf16*)R1;                 // [16][768][512]
    bf16*  Qb   = (bf16*)R1;                 // [16][8][768][64] (after Kc dead)
    bf16*  Kb   = (bf16*)(R1 + 12582912);
    bf16*  v_iT = (bf16*)R2;                 // [16][512][768]
    bf16*  VTb  = (bf16*)R2;                 // [16][8][64][768] (after v_iT dead)
    bf16*  c_x1 = (bf16*)R3;
    bf16*  Hout = (bf16*)R4;

    // TM=64 plain GEMM launcher
    auto G64 = [&](const bf16* A, const bf16* B, void* C, bool outBf,
                   int M, int N, int K, int lda, int ldb, int ldc,
                   long sA, long sB, long sC, int batch, float alpha, const float* bias) {
        dim3 grid(N / 128, M / 64, batch);
        if (outBf) gemm_bf16<bf16, 0, 64><<<grid, 256, 0, stream>>>(A, B, (bf16*)C, K, lda, ldb, ldc, sA, sB, sC, alpha, bias, 0, 0, 0, 0, nullptr, nullptr);
        else       gemm_bf16<float, 0, 64><<<grid, 256, 0, stream>>>(A, B, (float*)C, K, lda, ldb, ldc, sA, sB, sC, alpha, bias, 0, 0, 0, 0, nullptr, nullptr);
    };

    // ---- stage 0: one cast dispatch (x1, x2, zb, Wj) + 3 transposes ----
    k_cast3<<<dim3(3072, 1, 4), 256, 0, stream>>>(x1, x2, z_b, Wqkv_j,
                                                  c_x1, c_cat + 512, c_zb, Wj_bf);
    k_transpose<float, 3><<<dim3(24, 8, 3), 256, 0, stream>>>(
        Wqkv_i, Wqkv_b, W_QKV, nullptr, Wt4, 1536, 512, 0, 1536L * 512, 1, 0);
    k_transpose<float, 1><<<dim3(8, 16, 1), 256, 0, stream>>>(
        W_f, nullptr, nullptr, nullptr, Wt_f, 512, 1024, 0, 0, 1, 0);
    k_transpose<float, 2><<<dim3(8, 8, 2), 256, 0, stream>>>(
        W_m, W_proj, nullptr, nullptr, Wt_mp, 512, 512, 0, 512L * 512, 1, 0);

    // 1. qkvb = (0.2 zb) @ Wqkv_b               [256,1536] bf16
    G64(c_zb, Wt_b, qkvb, true, 256, 1536, 512, 512, 512, 1536, 0, 0, 0, 1, 1.f, nullptr);
    // 1b. G = k_b @ Wj^T  [256,512] bf16  (batch-shared; replaces qj GEMM:
    //     S3 = (x2@Wj)@k_b^T == x2@G^T by associativity)
    G64(qkvb + 512, Wj_bf, Gbuf, true, 256, 512, 512, 1536, 512, 512, 0, 0, 0, 1, 1.f, nullptr);
    // v_b^T -> Bcat[:, :, 256:512], replicated over all 16 batches
    k_transpose<bf16, 1><<<dim3(8, 4, 1), 256, 0, stream>>>(
        qkvb + 1024, nullptr, nullptr, nullptr, Bcat + 256, 1536, 512, 0, 0, 16, 512L * 512);
    // 2. [k_i|v_i] = x1 @ Wqkv_i[:,512:]  -> Kc compact + v_iT transposed
    gemm_bf16<bf16, 5, 128><<<dim3(8, 96, 1), 256, 0, stream>>>(
        c_x1, Wt_i + 512 * 512, Kc, 512, 512, 512, 512, 0, 0, 0,
        1.f, nullptr, 0, 0, 0, 0, nullptr, v_iT);
    // 4. S1 = scale * q_b @ k_i^T               [16][256,768] f32
    G64(qkvb, Kc, S, false, 256, 768, 512, 1536, 512, 768, 0, 768L * 512, 256L * 768, 16, scale, nullptr);
    softmax_wave<768, 0><<<1024, 256, 0, stream>>>(S, Sb1);
    // 5. aib0 = softmax1 @ v_i  -> aib0 + Bcat[:, :, 0:256]   [dual write]
    gemm_bf16<bf16, 6, 64><<<dim3(4, 4, 16), 256, 0, stream>>>(
        Sb1, v_iT, aib0, 768, 768, 768, 512, 256L * 768, 512L * 768, 256L * 512,
        1.f, nullptr, 0, 0, 512, 512L * 512, nullptr, Bcat);
    // 6+8. merged S2/S3: z<16: x1 @ aib0^T; z>=16: x2 @ G^T   [32][768,256]
    gemm_bf16<float, 7, 64><<<dim3(2, 12, 32), 256, 0, stream>>>(
        c_x1, aib0, S, 512, 512, 512, 256, 768L * 512, 256L * 512, 768L * 256,
        scale, nullptr, /*lda2=*/1024, /*sA2=*/768L * 1024, /*eld=*/512, 0,
        c_cat + 512, Gbuf);
    softmax_wave<256, 1><<<6144, 256, 0, stream>>>(S, Sb_cat);
    // 7+9+10. a_ij = 0.5 * [P2|P3] @ [aib0; v_b]  -> c_cat[:, :512] bf16
    G64(Sb_cat, Bcat, c_cat, true, 768, 512, 512, 512, 512, 1024,
        768L * 512, 512L * 512, 768L * 1024, 16, 0.5f, nullptr);
    // 11+12. fused gate: hbuf = relu(x1 + (a_ij@W_m + b_m)*sigmoid([a_ij|x2]@W_f + b_f))
    gemm_gate<<<dim3(4, 192), 256, 0, stream>>>(c_cat, Wt_f, Wt_m, hbuf, b_f, b_m, x1);
    // 13. QKV = h @ W_QKV -> head-separated Qb/Kb/VTb      [fused scatter]
    gemm_bf16<bf16, 4, 128><<<dim3(12, 96, 1), 256, 0, stream>>>(
        hbuf, Wt_qkv, Qb, 512, 512, 512, 0, 0, 0, 0,
        1.f, nullptr, 0, 0, 0, 0, Kb, VTb);
    // 14. MFMA flash MHSA -> Hout bf16
    mhsa_flash_mfma<<<dim3(8, 16, 12), 256, 0, stream>>>(Qb, Kb, VTb, Hout);
    // 15. out = Hout @ W_proj + b_proj          f32
    G64(Hout, Wt_proj, out, false, 12288, 512, 512, 512, 512, 512, 0, 0, 0, 1, 1.f, b_proj);
}

// Round 12
// 374.660 us; speedup vs baseline: 1.1182x; 1.0157x over previous
//
#include <hip/hip_runtime.h>
#include <hip/hip_bf16.h>

typedef __attribute__((ext_vector_type(8))) short short8;
typedef __attribute__((ext_vector_type(4))) float f32x4;
typedef __hip_bfloat16 bf16;
typedef unsigned short ushort;

__device__ __forceinline__ ushort f2b(float v) {
    bf16 h = __float2bfloat16(v);
    return *reinterpret_cast<ushort*>(&h);
}
__device__ __forceinline__ float b2f(ushort u) {
    return __uint_as_float((unsigned)u << 16);
}

#define GLD16(lds, gp) __builtin_amdgcn_global_load_lds( \
    (const __attribute__((address_space(1))) void*)(gp), \
    (__attribute__((address_space(3))) void*)(lds), 16, 0, 0)

// XCD-affinity swizzle (R3-verified: gate FETCH 64.6->37MB). Bijective when
// gridDim.y%8==0 and z==1; otherwise identity. Perf heuristic only.
__device__ __forceinline__ void xcd_swizzle(int& bx, int& by) {
    if (gridDim.z == 1 && (gridDim.y & 7) == 0) {
        const int id = bx + gridDim.x * by;
        const int xcd = id & 7, slot = id >> 3;
        by = xcd * (gridDim.y >> 3) + slot / gridDim.x;
        bx = slot - (slot / gridDim.x) * gridDim.x;
    }
}

// ---------------------------------------------------------------------------
// bf16 MFMA GEMM: C = alpha * A @ B^T (+ bias) with fused epilogues.
// R12 staged core (R4/R15 proved operand-direct is worse: loads issued
// inside the compute phase expose latency serially). Coalesced row-major
// [r][32] chunk-rotation LDS layout (bank-conflict 0). 2-phase double-
// buffer, one __syncthreads per phase, all loads a full phase ahead.
// TM=64: BK=64 phases (2 planes/buffer). TM=128: BK=32 (m132).
// R17 TN=64 variant: 32x32 wave quadrants, 1 B-GLD16/wave, for GRID-
// STARVED dispatches (steps 1/1b/4/5 ran at 1-1.5 blocks/CU = near-zero
// TLP; smaller tiles double block count). Same k-chunk order -> outputs
// bit-identical. Pipe-bound dispatches keep TN=128.
// EPI 0: plain.
// EPI 4: QKV head-scatter: C=Qb, px=Kb, py=VT   [b][h][n][hd] / [b][h][hd][n]
// EPI 5: KV split: C=Kc [b][n][512], py=v_iT [b][hd][768]
// EPI 6: dual write: C normal + py transposed (eld=transposed ld, sE=batch str)
// EPI 7: batched-pair: z<16 uses (A,lda,sA,B,ldb,sB); z>=16 uses
//        (px,lda2,sA2, py,eld,sB=0)  [z>=16 = x2 @ G^T]
// ---------------------------------------------------------------------------
template<typename OutT, int EPI, int TM, int TN = 128>
__global__ __launch_bounds__(256) void gemm_bf16(
    const bf16* __restrict__ A, const bf16* __restrict__ B, OutT* __restrict__ C,
    int K, int lda, int ldb, int ldc, long sA, long sB, long sC,
    float alpha, const float* __restrict__ bias,
    int lda2, long sA2, int eld, long sE,
    bf16* __restrict__ px, bf16* __restrict__ py)
{
    constexpr int RT = TM / 32;              // row MFMA-tiles per wave
    constexpr int CT = TN / 32;              // col MFMA-tiles per wave
    constexpr int PLA = TM * 32;             // halfwords per 32-k A plane
    constexpr int PLB = TN * 32;
    constexpr int NP = (TM == 64) ? 4 : 2;   // planes total (2 bufs x {2,1})
    __shared__ __align__(16) bf16 As[NP * PLA];
    __shared__ __align__(16) bf16 Bs[NP * PLB];

    const int t = threadIdx.x;
    const int w = t >> 6, lane = t & 63;
    const int wr = w >> 1, wc = w & 1;
    const int lr = lane & 15, kc4 = lane >> 4;
    const int qr = lane >> 2;                              // row within 16-row slice
    const int kcr = ((lane & 3) - ((lane >> 3) & 3)) & 3;  // rotated global k-chunk
    int bx = blockIdx.x, by = blockIdx.y;
    xcd_swizzle(bx, by);
    const int row0 = by * TM, col0 = bx * TN;
    const int bz = blockIdx.z;

    const bf16* Asel = A; const bf16* Bsel = B;
    int abz = bz; long sBe = sB, sAe = sA; int ldbe = ldb, ldae = lda;
    if constexpr (EPI == 7) {
        if (bz >= 16) {
            Asel = (const bf16*)px; Bsel = (const bf16*)py;
            abz = bz - 16; sBe = 0; ldbe = eld; ldae = lda2; sAe = sA2;
        }
    }
    const bf16* Ab = Asel + (size_t)abz * sAe + (size_t)row0 * ldae;
    const bf16* Bb = Bsel + (size_t)abz * sBe + (size_t)col0 * ldbe;

    // staging: each GLD16 covers 16 rows x 64B (4 lanes/row, coalesced)
    const bf16* ga0; const bf16* ga1 = nullptr;
    if constexpr (TM == 64) {
        ga0 = Ab + (size_t)(w * 16 + qr) * ldae + kcr * 8;
    } else {
        ga0 = Ab + (size_t)(w * 32 + qr) * ldae + kcr * 8;
        ga1 = Ab + (size_t)(w * 32 + 16 + qr) * ldae + kcr * 8;
    }
    const bf16* gb0; const bf16* gb1 = nullptr;
    if constexpr (TN == 128) {
        gb0 = Bb + (size_t)(w * 32 + qr) * ldbe + kcr * 8;
        gb1 = Bb + (size_t)(w * 32 + 16 + qr) * ldbe + kcr * 8;
    } else {
        gb0 = Bb + (size_t)(w * 16 + qr) * ldbe + kcr * 8;
    }
    bf16* lA0; bf16* lA1 = nullptr;
    if constexpr (TM == 64) { lA0 = &As[w * 512]; }
    else                    { lA0 = &As[w * 1024]; lA1 = &As[w * 1024 + 512]; }
    bf16* lB0; bf16* lB1 = nullptr;
    if constexpr (TN == 128) { lB0 = &Bs[w * 1024]; lB1 = &Bs[w * 1024 + 512]; }
    else                     { lB0 = &Bs[w * 512]; }

    f32x4 acc[RT][CT] = {};

    const int cSw = ((kc4 + ((lr >> 1) & 3)) & 3) * 8;     // swizzled chunk offset
    const bf16* ApBase = &As[(wr * (TM / 2) + lr) * 32 + cSw];
    const bf16* BpBase = &Bs[(wc * (TN / 2) + lr) * 32 + cSw];

    auto stageP = [&](int plane, int ko) {
        GLD16(lA0 + plane * PLA, ga0 + ko);
        if constexpr (TM == 128) GLD16(lA1 + plane * PLA, ga1 + ko);
        GLD16(lB0 + plane * PLB, gb0 + ko);
        if constexpr (TN == 128) GLD16(lB1 + plane * PLB, gb1 + ko);
    };
    auto compP = [&](int plane) {
        const bf16* Ap = ApBase + plane * PLA;
        const bf16* Bp = BpBase + plane * PLB;
        short8 af[RT], bfr[CT];
#pragma unroll
        for (int i = 0; i < RT; ++i) af[i]  = *(const short8*)(Ap + i * 512);
#pragma unroll
        for (int j = 0; j < CT; ++j) bfr[j] = *(const short8*)(Bp + j * 512);
#pragma unroll
        for (int i = 0; i < RT; ++i)
#pragma unroll
            for (int j = 0; j < CT; ++j)
                acc[i][j] = __builtin_amdgcn_mfma_f32_16x16x32_bf16(af[i], bfr[j], acc[i][j], 0, 0, 0);
    };

    if constexpr (TM == 64) {
        stageP(0, 0); stageP(1, 32);        // prologue: buffer 0, planes 0..1
        int buf = 0;
        for (int k0 = 0; k0 < K; k0 += 64) {   // K % 64 == 0 at all call sites
            __syncthreads();                   // cur buf staged; other buf free
            if (k0 + 64 < K) {
                stageP((buf ^ 1) * 2,     k0 + 64);
                stageP((buf ^ 1) * 2 + 1, k0 + 96);
            }
            compP(buf * 2); compP(buf * 2 + 1);
            buf ^= 1;
        }
    } else {
        stageP(0, 0);
        int buf = 0;
        for (int k0 = 0; k0 < K; k0 += 32) {
            __syncthreads();
            if (k0 + 32 < K) stageP(buf ^ 1, k0 + 32);
            compP(buf);
            buf ^= 1;
        }
    }

    if constexpr (EPI == 4) {
        const int sec = bx >> 2;                    // 0=q 1=k 2=v
        const int h0 = (bx & 3) * 2;
        const int b  = by / 6;
        const int n0 = (by % 6) * TM;
        bf16* dq = (bf16*)C;
#pragma unroll
        for (int j = 0; j < CT; ++j) {
            const int col = wc * 64 + j * 16 + lr;
            const int h = h0 + (col >> 6), hd = col & 63;
            const size_t bh = (size_t)b * 8 + h;
#pragma unroll
            for (int i = 0; i < RT; ++i) {
                const int n = n0 + wr * (TM / 2) + i * 16 + kc4 * 4;
                if (sec == 2) {
                    __align__(8) ushort o[4];
#pragma unroll
                    for (int r = 0; r < 4; ++r) o[r] = f2b(acc[i][j][r]);
                    *(int2*)&py[(bh * 64 + hd) * 768 + n] = *(const int2*)o;
                } else {
                    bf16* d = (sec == 0) ? dq : px;
#pragma unroll
                    for (int r = 0; r < 4; ++r)
                        d[(bh * 768 + n + r) * 64 + hd] = __float2bfloat16(acc[i][j][r]);
                }
            }
        }
        return;
    } else if constexpr (EPI == 5) {
        const int b  = by / 6;
        const int n0 = (by % 6) * TM;
#pragma unroll
        for (int j = 0; j < CT; ++j) {
            const int col = col0 + wc * 64 + j * 16 + lr;
#pragma unroll
            for (int i = 0; i < RT; ++i) {
                const int n = n0 + wr * (TM / 2) + i * 16 + kc4 * 4;
                if (col < 512) {
#pragma unroll
                    for (int r = 0; r < 4; ++r)
                        ((bf16*)C)[((size_t)b * 768 + n + r) * 512 + col] = __float2bfloat16(acc[i][j][r]);
                } else {
                    __align__(8) ushort o[4];
#pragma unroll
                    for (int r = 0; r < 4; ++r) o[r] = f2b(acc[i][j][r]);
                    *(int2*)&py[((size_t)b * 512 + (col - 512)) * 768 + n] = *(const int2*)o;
                }
            }
        }
        return;
    }

    OutT* Cb = C + (size_t)bz * sC;
#pragma unroll
    for (int j = 0; j < CT; ++j) {
        const int col = col0 + wc * (TN / 2) + j * 16 + lr;
        const float bv = bias ? bias[col] : 0.f;
#pragma unroll
        for (int i = 0; i < RT; ++i) {
            const int rb = row0 + wr * (TM / 2) + i * 16 + kc4 * 4;
            if constexpr (EPI == 6) {
                __align__(8) ushort o[4];
#pragma unroll
                for (int r = 0; r < 4; ++r) {
                    o[r] = f2b(alpha * acc[i][j][r]);
                    Cb[(size_t)(rb + r) * ldc + col] = __float2bfloat16(alpha * acc[i][j][r]);
                }
                *(int2*)&py[(size_t)bz * sE + (size_t)col * eld + rb] = *(const int2*)o;
            } else {
#pragma unroll
                for (int r = 0; r < 4; ++r) {
                    const int row = rb + r;
                    float v = alpha * acc[i][j][r] + bv;
                    if constexpr (sizeof(OutT) == 2)
                        Cb[(size_t)row * ldc + col] = __float2bfloat16(v);
                    else
                        Cb[(size_t)row * ldc + col] = v;
                }
            }
        }
    }
}

// ---------------------------------------------------------------------------
// Fused gate GEMM (steps 11+12), grid (4,192) = 768 (3 blk/CU).
// R9 shared-A form (best measured) + XCD swizzle. Per 32-k phase: stage
// A(1)+F(2)+M(2 while k<512) GLD16/wave; compute 8 F-MFMA (+8 M-MFMA
// sharing the A fragments). LDS 40KB. Kept TN=128 (pipe-bound, not
// grid-starved).
// ---------------------------------------------------------------------------
__global__ __launch_bounds__(256) void gemm_gate(
    const bf16* __restrict__ A, const bf16* __restrict__ Bf,
    const bf16* __restrict__ Bm, bf16* __restrict__ Cout,
    const float* __restrict__ bias_f, const float* __restrict__ bias_m,
    const float* __restrict__ x1)
{
    constexpr int AHW = 64 * 32;
    constexpr int BHW = 128 * 32;
    __shared__ __align__(16) bf16 As[2 * AHW];
    __shared__ __align__(16) bf16 FsS[2 * BHW];
    __shared__ __align__(16) bf16 MsS[2 * BHW];

    const int t = threadIdx.x;
    const int w = t >> 6, lane = t & 63;
    const int wr = w >> 1, wc = w & 1;
    const int lr = lane & 15, kc4 = lane >> 4;
    const int qr = lane >> 2;
    const int kcr = ((lane & 3) - ((lane >> 3) & 3)) & 3;
    int bx = blockIdx.x, by = blockIdx.y;
    xcd_swizzle(bx, by);
    const int row0 = by * 64, col0 = bx * 128;

    const bf16* ga0 = A  + (size_t)(row0 + w * 16 + qr) * 1024 + kcr * 8;
    const bf16* gf0 = Bf + (size_t)(col0 + w * 32 + qr) * 1024 + kcr * 8;
    const bf16* gf1 = Bf + (size_t)(col0 + w * 32 + 16 + qr) * 1024 + kcr * 8;
    const bf16* gm0 = Bm + (size_t)(col0 + w * 32 + qr) * 512 + kcr * 8;
    const bf16* gm1 = Bm + (size_t)(col0 + w * 32 + 16 + qr) * 512 + kcr * 8;
    bf16* lA0 = &As[w * 512];
    bf16* lF0 = &FsS[w * 1024]; bf16* lF1 = &FsS[w * 1024 + 512];
    bf16* lM0 = &MsS[w * 1024]; bf16* lM1 = &MsS[w * 1024 + 512];

    f32x4 acc1[2][4] = {};   // fg
    f32x4 acc2[2][4] = {};   // hm

    const int cSw = ((kc4 + ((lr >> 1) & 3)) & 3) * 8;
    const bf16* ApBase = &As[(wr * 32 + lr) * 32 + cSw];
    const bf16* FpBase = &FsS[(wc * 64 + lr) * 32 + cSw];
    const bf16* MpBase = &MsS[(wc * 64 + lr) * 32 + cSw];

    // prologue: stage k=0 into buffer 0
    GLD16(lA0, ga0);
    GLD16(lF0, gf0); GLD16(lF1, gf1);
    GLD16(lM0, gm0); GLD16(lM1, gm1);

    auto step = [&](int kk, int rd, int st) {
        __syncthreads();
        const int kn = kk + 32;
        if (kn < 1024) {
            GLD16(lA0 + st * AHW, ga0 + kn);
            GLD16(lF0 + st * BHW, gf0 + kn);
            GLD16(lF1 + st * BHW, gf1 + kn);
            if (kn < 512) {
                GLD16(lM0 + st * BHW, gm0 + kn);
                GLD16(lM1 + st * BHW, gm1 + kn);
            }
        }
        const bf16* Ap = ApBase + rd * AHW;
        const bf16* Fp = FpBase + rd * BHW;
        short8 af[2], ff[4];
#pragma unroll
        for (int i = 0; i < 2; ++i) af[i] = *(const short8*)(Ap + i * 512);
#pragma unroll
        for (int j = 0; j < 4; ++j) ff[j] = *(const short8*)(Fp + j * 512);
#pragma unroll
        for (int i = 0; i < 2; ++i)
#pragma unroll
            for (int j = 0; j < 4; ++j)
                acc1[i][j] = __builtin_amdgcn_mfma_f32_16x16x32_bf16(af[i], ff[j], acc1[i][j], 0, 0, 0);
        if (kk < 512) {
            const bf16* Mp = MpBase + rd * BHW;
            short8 mf[4];
#pragma unroll
            for (int j = 0; j < 4; ++j) mf[j] = *(const short8*)(Mp + j * 512);
#pragma unroll
            for (int i = 0; i < 2; ++i)
#pragma unroll
                for (int j = 0; j < 4; ++j)
                    acc2[i][j] = __builtin_amdgcn_mfma_f32_16x16x32_bf16(af[i], mf[j], acc2[i][j], 0, 0, 0);
        }
    };

    for (int k0 = 0; k0 < 1024; k0 += 64) {
        step(k0, 0, 1);
        step(k0 + 32, 1, 0);
    }

#pragma unroll
    for (int j = 0; j < 4; ++j) {
        const int col = col0 + wc * 64 + j * 16 + lr;
        const float bvf = bias_f[col], bvm = bias_m[col];
#pragma unroll
        for (int i = 0; i < 2; ++i) {
            const int rb = row0 + wr * 32 + i * 16 + kc4 * 4;
#pragma unroll
            for (int r = 0; r < 4; ++r) {
                const int row = rb + r;
                const float sig = 1.f / (1.f + __expf(-(acc1[i][j][r] + bvf)));
                const float rr = x1[(size_t)row * 512 + col] + (acc2[i][j][r] + bvm) * sig;
                Cout[(size_t)row * 512 + col] = __float2bfloat16(rr > 0.f ? rr : 0.f);
            }
        }
    }
}

// ---------------------------------------------------------------------------
// Transpose + cast to bf16: src [R,C] -> dst [C,R] bf16. Multi-source via z.
// rep/repStride: replicate the transposed output (for broadcast B panels).
// ---------------------------------------------------------------------------
template<typename TI, int NSRC>
__global__ __launch_bounds__(256) void k_transpose(
    const TI* __restrict__ s0, const TI* __restrict__ s1,
    const TI* __restrict__ s2, const TI* __restrict__ s3,
    bf16* __restrict__ dst, int src_ld, int dst_ld, long sSrc, long sDst,
    int rep, long repStride)
{
    __shared__ float tile[64][65];
    const int t = threadIdx.x;
    const int c0 = blockIdx.x * 64, r0 = blockIdx.y * 64;
    const int z = blockIdx.z;
    const TI* src = s0;
    if (NSRC > 1) src = (z == 0) ? s0 : (z == 1) ? s1 : (z == 2) ? s2 : s3;
    {
        const int r = t >> 2, cq = (t & 3) * 16;
        const TI* sp = src + (size_t)z * sSrc + (size_t)(r0 + r) * src_ld + c0 + cq;
        if constexpr (sizeof(TI) == 4) {
#pragma unroll
            for (int u = 0; u < 16; u += 4) {
                float4 v = *(const float4*)((const float*)sp + u);
                tile[r][cq + u]     = v.x; tile[r][cq + u + 1] = v.y;
                tile[r][cq + u + 2] = v.z; tile[r][cq + u + 3] = v.w;
            }
        } else {
            const ushort* up = (const ushort*)sp;
            union { short8 v; ushort u[8]; } p0, p1;
            p0.v = *(const short8*)up; p1.v = *(const short8*)(up + 8);
#pragma unroll
            for (int u = 0; u < 8; ++u) {
                tile[r][cq + u]     = b2f(p0.u[u]);
                tile[r][cq + 8 + u] = b2f(p1.u[u]);
            }
        }
    }
    __syncthreads();
    const int c = t >> 2, rq = (t & 3) * 16;
    __align__(16) ushort ob[16];
#pragma unroll
    for (int u = 0; u < 16; ++u) ob[u] = f2b(tile[rq + u][c]);
    for (int rp = 0; rp < rep; ++rp) {
        bf16* dp = dst + (size_t)rp * repStride + (size_t)z * sDst + (size_t)(c0 + c) * dst_ld + r0 + rq;
        *(int4*)dp       = *(const int4*)&ob[0];
        *(int4*)(dp + 8) = *(const int4*)&ob[8];
    }
}

// input casts in one dispatch (z selects job). z==3: strided read of
// Wqkv_j[:, :512] (f32 ld 1536) -> Wj_bf [512][512] bf16 (for the G trick).
__global__ __launch_bounds__(256) void k_cast3(const float* __restrict__ x1,
    const float* __restrict__ x2, const float* __restrict__ zb,
    const float* __restrict__ wj,
    bf16* __restrict__ d1, bf16* __restrict__ d2, bf16* __restrict__ d3,
    bf16* __restrict__ d4)
{
    const int z = blockIdx.z;
    const float* src; bf16* dst; int ld; float scale; int n;
    if (z == 0)      { src = x1; dst = d1; ld = 512;  scale = 1.f;  n = 6291456; }
    else if (z == 1) { src = x2; dst = d2; ld = 1024; scale = 1.f;  n = 6291456; }
    else if (z == 2) { src = zb; dst = d3; ld = 512;  scale = 0.2f; n = 131072;  }
    else             { src = wj; dst = d4; ld = 512;  scale = 1.f;  n = 262144;  }
    int i = (blockIdx.x * 256 + threadIdx.x) * 8;
    if (i >= n) return;
    int si = i;
    if (z == 3) si = (i >> 9) * 1536 + (i & 511);
    float4 a = *(const float4*)(src + si), b = *(const float4*)(src + si + 4);
    __align__(16) ushort o[8];
    o[0] = f2b(a.x * scale); o[1] = f2b(a.y * scale); o[2] = f2b(a.z * scale); o[3] = f2b(a.w * scale);
    o[4] = f2b(b.x * scale); o[5] = f2b(b.y * scale); o[6] = f2b(b.z * scale); o[7] = f2b(b.w * scale);
    int row = i >> 9, col = i & 511;
    *(int4*)(dst + (size_t)row * ld + col) = *(const int4*)o;
}

// ---------------------------------------------------------------------------
// Wave-per-row softmax f32 -> bf16. 4 rows/block (one per wave), no barriers.
// MODE 0: dst = Y + row*COLS.
// MODE 1 (merged S2/S3, COLS=256): row = z*768+m, z in [0,32);
//   dst = Y + ((z&15)*768+m)*512 + (z>>4)*256   (K-concat layout).
// ---------------------------------------------------------------------------
template<int COLS, int MODE>
__global__ __launch_bounds__(256) void softmax_wave(const float* __restrict__ X,
                                                    bf16* __restrict__ Y)
{
    const int wv = threadIdx.x >> 6, lane = threadIdx.x & 63;
    const long row = (long)blockIdx.x * 4 + wv;
    const float* src = X + row * COLS;
    constexpr int V = COLS / 64;
    float v[V];
#pragma unroll
    for (int i = 0; i < V; ++i) v[i] = src[lane + i * 64];
    float m = v[0];
#pragma unroll
    for (int i = 1; i < V; ++i) m = fmaxf(m, v[i]);
#pragma unroll
    for (int o = 32; o; o >>= 1) m = fmaxf(m, __shfl_xor(m, o));
    float s = 0.f;
#pragma unroll
    for (int i = 0; i < V; ++i) { v[i] = __expf(v[i] - m); s += v[i]; }
#pragma unroll
    for (int o = 32; o; o >>= 1) s += __shfl_xor(s, o);
    const float inv = 1.f / s;
    bf16* dst;
    if constexpr (MODE == 0) {
        dst = Y + row * COLS;
    } else {
        const int z = (int)(row / 768), mm = (int)(row % 768);
        dst = Y + ((size_t)(z & 15) * 768 + mm) * 512 + (z >> 4) * 256;
    }
#pragma unroll
    for (int i = 0; i < V; ++i) dst[lane + i * 64] = __float2bfloat16(v[i] * inv);
}

// ---------------------------------------------------------------------------
// MFMA flash MHSA v4 (verified R7): no online max (scores O(1), exp safe),
// unnormalized P accumulation, single end reduction. Head-separated inputs,
// head-major grid for L2 pinning.
// ---------------------------------------------------------------------------
__global__ __launch_bounds__(256) void mhsa_flash_mfma(
    const bf16* __restrict__ Qb, const bf16* __restrict__ Kb,
    const bf16* __restrict__ VT, bf16* __restrict__ Hout)
{
    constexpr int LD = 72;
    __shared__ __align__(16) ushort Qs[64 * LD];
    __shared__ __align__(16) ushort Ks[64 * LD];
    __shared__ __align__(16) ushort Vt[64 * LD];
    __shared__ __align__(16) ushort Ps[64 * LD];

    const int t = threadIdx.x;
    const int w = t >> 6, lane = t & 63;
    const int l16 = lane & 15, q4 = lane >> 4;
    const int h = blockIdx.x, b = blockIdx.y, qt = blockIdx.z;
    const size_t bh = (size_t)b * 8 + h;
    const ushort* qbase = (const ushort*)Qb + bh * 768 * 64;
    const ushort* kbase = (const ushort*)Kb + bh * 768 * 64;
    const ushort* vbase = (const ushort*)VT + bh * 64 * 768;

    const int r = t >> 2, c0 = (t & 3) * 16;

    {
        const ushort* src = qbase + (size_t)(qt * 64 + r) * 64 + c0;
        *(int4*)&Qs[r * LD + c0]     = *(const int4*)src;
        *(int4*)&Qs[r * LD + c0 + 8] = *(const int4*)(src + 8);
    }

    int4 ka0, ka1, va0, va1;
    {
        const ushort* ks = kbase + (size_t)r * 64 + c0;
        ka0 = *(const int4*)ks; ka1 = *(const int4*)(ks + 8);
        const ushort* vs = vbase + (size_t)r * 768 + c0;
        va0 = *(const int4*)vs; va1 = *(const int4*)(vs + 8);
    }
    __syncthreads();

    short8 qf0 = *(const short8*)&Qs[(w * 16 + l16) * LD + q4 * 8];
    short8 qf1 = *(const short8*)&Qs[(w * 16 + l16) * LD + 32 + q4 * 8];

    float lsum[4] = {0.f, 0.f, 0.f, 0.f};
    f32x4 acc[4] = {};

    for (int kt = 0; kt < 12; ++kt) {
        if (kt) __syncthreads();
        *(int4*)&Ks[r * LD + c0]     = ka0;
        *(int4*)&Ks[r * LD + c0 + 8] = ka1;
        *(int4*)&Vt[r * LD + c0]     = va0;
        *(int4*)&Vt[r * LD + c0 + 8] = va1;
        __syncthreads();

        if (kt < 11) {
            const ushort* ks = kbase + (size_t)((kt + 1) * 64 + r) * 64 + c0;
            ka0 = *(const int4*)ks; ka1 = *(const int4*)(ks + 8);
            const ushort* vs = vbase + (size_t)r * 768 + (kt + 1) * 64 + c0;
            va0 = *(const int4*)vs; va1 = *(const int4*)(vs + 8);
        }

        f32x4 s[4] = {};
#pragma unroll
        for (int nt = 0; nt < 4; ++nt) {
            short8 kf0 = *(const short8*)&Ks[(nt * 16 + l16) * LD + q4 * 8];
            short8 kf1 = *(const short8*)&Ks[(nt * 16 + l16) * LD + 32 + q4 * 8];
            s[nt] = __builtin_amdgcn_mfma_f32_16x16x32_bf16(qf0, kf0, s[nt], 0, 0, 0);
            s[nt] = __builtin_amdgcn_mfma_f32_16x16x32_bf16(qf1, kf1, s[nt], 0, 0, 0);
        }

#pragma unroll
        for (int nt = 0; nt < 4; ++nt) {
#pragma unroll
            for (int e = 0; e < 4; ++e) {
                const float p = __expf(s[nt][e] * 0.125f);
                lsum[e] += p;
                Ps[(w * 16 + q4 * 4 + e) * LD + nt * 16 + l16] = f2b(p);
            }
        }

        short8 pf0 = *(const short8*)&Ps[(w * 16 + l16) * LD + q4 * 8];
        short8 pf1 = *(const short8*)&Ps[(w * 16 + l16) * LD + 32 + q4 * 8];
#pragma unroll
        for (int jt = 0; jt < 4; ++jt) {
            short8 vf0 = *(const short8*)&Vt[(jt * 16 + l16) * LD + q4 * 8];
            short8 vf1 = *(const short8*)&Vt[(jt * 16 + l16) * LD + 32 + q4 * 8];
            acc[jt] = __builtin_amdgcn_mfma_f32_16x16x32_bf16(pf0, vf0, acc[jt], 0, 0, 0);
            acc[jt] = __builtin_amdgcn_mfma_f32_16x16x32_bf16(pf1, vf1, acc[jt], 0, 0, 0);
        }
    }

    const int orow = qt * 64 + w * 16 + q4 * 4;
#pragma unroll
    for (int e = 0; e < 4; ++e) {
        float l = lsum[e];
        l += __shfl_xor(l, 1);
        l += __shfl_xor(l, 2);
        l += __shfl_xor(l, 4);
        l += __shfl_xor(l, 8);
        const float inv = 1.f / l;
        const size_t rbase = ((size_t)b * 768 + orow + e) * 512 + h * 64;
#pragma unroll
        for (int jt = 0; jt < 4; ++jt)
            Hout[rbase + jt * 16 + l16] = __float2bfloat16(acc[jt][e] * inv);
    }
}

// ---------------------------------------------------------------------------
extern "C" void kernel_launch(void* const* d_in, const int* in_sizes, int n_in,
                              void* d_out, int out_size, void* d_ws, size_t ws_size,
                              hipStream_t stream)
{
    (void)in_sizes; (void)n_in; (void)out_size; (void)ws_size;
    const float* x1     = (const float*)d_in[0];
    const float* x2     = (const float*)d_in[1];
    const float* z_b    = (const float*)d_in[2];
    const float* Wqkv_i = (const float*)d_in[3];
    const float* Wqkv_j = (const float*)d_in[4];
    const float* Wqkv_b = (const float*)d_in[5];
    const float* W_f    = (const float*)d_in[6];
    const float* b_f    = (const float*)d_in[7];
    const float* W_m    = (const float*)d_in[8];
    const float* b_m    = (const float*)d_in[9];
    const float* W_QKV  = (const float*)d_in[10];
    const float* W_proj = (const float*)d_in[11];
    const float* b_proj = (const float*)d_in[12];
    float* out = (float*)d_out;

    const float scale = 0.044194173824159216f;   // 512^-0.5

    char* base = (char*)d_ws;
    size_t off = 0;
    auto alloc = [&](size_t bytes) { char* r = base + off; off += (bytes + 255) & ~(size_t)255; return r; };

    char* Rq  = alloc((size_t)3 * 25165824);
    char* R1  = Rq;                 // Kc bf16 | Qb+Kb bf16
    char* R2  = Rq + 25165824;      // v_iT bf16 | VTb bf16
    char* R3  = Rq + 2 * 25165824;  // c_x1 bf16
    char* R4  = alloc(25165824);    // Hout bf16
    bf16* Wt4     = (bf16*)alloc((size_t)3 * 1536 * 512 * 2);  // i, b, qkv
    bf16* Wt_f    = (bf16*)alloc(512 * 1024 * 2);
    bf16* Wt_mp   = (bf16*)alloc((size_t)2 * 512 * 512 * 2);   // m, proj
    bf16* Wj_bf   = (bf16*)alloc(512 * 512 * 2);               // Wqkv_j[:, :512] bf16
    bf16* Gbuf    = (bf16*)alloc(256 * 512 * 2);               // G = k_b @ Wj^T
    bf16* c_zb    = (bf16*)alloc(256 * 512 * 2);
    bf16* qkvb    = (bf16*)alloc(256 * 1536 * 2);
    bf16* aib0    = (bf16*)alloc((size_t)16 * 256 * 512 * 2);
    bf16* Bcat    = (bf16*)alloc((size_t)16 * 512 * 512 * 2);  // [aib0^T | v_b^T]
    float* S      = (float*)alloc((size_t)32 * 768 * 256 * 4);
    bf16* Sb1     = (bf16*)alloc((size_t)16 * 256 * 768 * 2);
    bf16* Sb_cat  = (bf16*)alloc((size_t)16 * 768 * 512 * 2);  // [P2 | P3] K-concat
    bf16* c_cat   = (bf16*)alloc((size_t)12288 * 1024 * 2);
    bf16* hbuf    = (bf16*)alloc((size_t)12288 * 512 * 2);

    bf16* Wt_i = Wt4, *Wt_b = Wt4 + 1536 * 512,
        *Wt_qkv = Wt4 + (size_t)2 * 1536 * 512;
    bf16* Wt_m = Wt_mp, *Wt_proj = Wt_mp + 512 * 512;

    bf16*  Kc   = (bf16*)R1;                 // [16][768][512]
    bf16*  Qb   = (bf16*)R1;                 // [16][8][768][64] (after Kc dead)
    bf16*  Kb   = (bf16*)(R1 + 12582912);
    bf16*  v_iT = (bf16*)R2;                 // [16][512][768]
    bf16*  VTb  = (bf16*)R2;                 // [16][8][64][768] (after v_iT dead)
    bf16*  c_x1 = (bf16*)R3;
    bf16*  Hout = (bf16*)R4;

    // TM=64 plain GEMM launcher (TN=128)
    auto G64 = [&](const bf16* A, const bf16* B, void* C, bool outBf,
                   int M, int N, int K, int lda, int ldb, int ldc,
                   long sA, long sB, long sC, int batch, float alpha, const float* bias) {
        dim3 grid(N / 128, M / 64, batch);
        if (outBf) gemm_bf16<bf16, 0, 64><<<grid, 256, 0, stream>>>(A, B, (bf16*)C, K, lda, ldb, ldc, sA, sB, sC, alpha, bias, 0, 0, 0, 0, nullptr, nullptr);
        else       gemm_bf16<float, 0, 64><<<grid, 256, 0, stream>>>(A, B, (float*)C, K, lda, ldb, ldc, sA, sB, sC, alpha, bias, 0, 0, 0, 0, nullptr, nullptr);
    };
    // TN=64 launcher for grid-starved dispatches (2x blocks)
    auto G64n = [&](const bf16* A, const bf16* B, void* C, bool outBf,
                    int M, int N, int K, int lda, int ldb, int ldc,
                    long sA, long sB, long sC, int batch, float alpha, const float* bias) {
        dim3 grid(N / 64, M / 64, batch);
        if (outBf) gemm_bf16<bf16, 0, 64, 64><<<grid, 256, 0, stream>>>(A, B, (bf16*)C, K, lda, ldb, ldc, sA, sB, sC, alpha, bias, 0, 0, 0, 0, nullptr, nullptr);
        else       gemm_bf16<float, 0, 64, 64><<<grid, 256, 0, stream>>>(A, B, (float*)C, K, lda, ldb, ldc, sA, sB, sC, alpha, bias, 0, 0, 0, 0, nullptr, nullptr);
    };

    // ---- stage 0: one cast dispatch (x1, x2, zb, Wj) + 3 transposes ----
    k_cast3<<<dim3(3072, 1, 4), 256, 0, stream>>>(x1, x2, z_b, Wqkv_j,
                                                  c_x1, c_cat + 512, c_zb, Wj_bf);
    k_transpose<float, 3><<<dim3(24, 8, 3), 256, 0, stream>>>(
        Wqkv_i, Wqkv_b, W_QKV, nullptr, Wt4, 1536, 512, 0, 1536L * 512, 1, 0);
    k_transpose<float, 1><<<dim3(8, 16, 1), 256, 0, stream>>>(
        W_f, nullptr, nullptr, nullptr, Wt_f, 512, 1024, 0, 0, 1, 0);
    k_transpose<float, 2><<<dim3(8, 8, 2), 256, 0, stream>>>(
        W_m, W_proj, nullptr, nullptr, Wt_mp, 512, 512, 0, 512L * 512, 1, 0);

    // 1. qkvb = (0.2 zb) @ Wqkv_b   [256,1536] bf16   [TN=64: 48->96 blocks]
    G64n(c_zb, Wt_b, qkvb, true, 256, 1536, 512, 512, 512, 1536, 0, 0, 0, 1, 1.f, nullptr);
    // 1b. G = k_b @ Wj^T  [256,512] bf16  (S3 = x2@G^T)  [TN=64: 16->32 blk]
    G64n(qkvb + 512, Wj_bf, Gbuf, true, 256, 512, 512, 1536, 512, 512, 0, 0, 0, 1, 1.f, nullptr);
    // v_b^T -> Bcat[:, :, 256:512], replicated over all 16 batches
    k_transpose<bf16, 1><<<dim3(8, 4, 1), 256, 0, stream>>>(
        qkvb + 1024, nullptr, nullptr, nullptr, Bcat + 256, 1536, 512, 0, 0, 16, 512L * 512);
    // 2. [k_i|v_i] = x1 @ Wqkv_i[:,512:]  -> Kc compact + v_iT transposed
    gemm_bf16<bf16, 5, 128><<<dim3(8, 96, 1), 256, 0, stream>>>(
        c_x1, Wt_i + 512 * 512, Kc, 512, 512, 512, 512, 0, 0, 0,
        1.f, nullptr, 0, 0, 0, 0, nullptr, v_iT);
    // 4. S1 = scale * q_b @ k_i^T  [16][256,768] f32  [TN=64: 384->768 blk]
    G64n(qkvb, Kc, S, false, 256, 768, 512, 1536, 512, 768, 0, 768L * 512, 256L * 768, 16, scale, nullptr);
    softmax_wave<768, 0><<<1024, 256, 0, stream>>>(S, Sb1);
    // 5. aib0 = softmax1 @ v_i -> aib0 + Bcat[:,:,0:256]  [TN=64: 256->512]
    gemm_bf16<bf16, 6, 64, 64><<<dim3(8, 4, 16), 256, 0, stream>>>(
        Sb1, v_iT, aib0, 768, 768, 768, 512, 256L * 768, 512L * 768, 256L * 512,
        1.f, nullptr, 0, 0, 512, 512L * 512, nullptr, Bcat);
    // 6+8. merged S2/S3: z<16: x1 @ aib0^T; z>=16: x2 @ G^T   [32][768,256]
    gemm_bf16<float, 7, 64><<<dim3(2, 12, 32), 256, 0, stream>>>(
        c_x1, aib0, S, 512, 512, 512, 256, 768L * 512, 256L * 512, 768L * 256,
        scale, nullptr, /*lda2=*/1024, /*sA2=*/768L * 1024, /*eld=*/512, 0,
        c_cat + 512, Gbuf);
    softmax_wave<256, 1><<<6144, 256, 0, stream>>>(S, Sb_cat);
    // 7+9+10. a_ij = 0.5 * [P2|P3] @ [aib0; v_b]  -> c_cat[:, :512] bf16
    G64(Sb_cat, Bcat, c_cat, true, 768, 512, 512, 512, 512, 1024,
        768L * 512, 512L * 512, 768L * 1024, 16, 0.5f, nullptr);
    // 11+12. fused gate: hbuf = relu(x1 + (a_ij@W_m + b_m)*sigmoid([a_ij|x2]@W_f + b_f))
    gemm_gate<<<dim3(4, 192), 256, 0, stream>>>(c_cat, Wt_f, Wt_m, hbuf, b_f, b_m, x1);
    // 13. QKV = h @ W_QKV -> head-separated Qb/Kb/VTb      [fused scatter]
    gemm_bf16<bf16, 4, 128><<<dim3(12, 96, 1), 256, 0, stream>>>(
        hbuf, Wt_qkv, Qb, 512, 512, 512, 0, 0, 0, 0,
        1.f, nullptr, 0, 0, 0, 0, Kb, VTb);
    // 14. MFMA flash MHSA -> Hout bf16
    mhsa_flash_mfma<<<dim3(8, 16, 12), 256, 0, stream>>>(Qb, Kb, VTb, Hout);
    // 15. out = Hout @ W_proj + b_proj          f32
    G64(Hout, Wt_proj, out, false, 12288, 512, 512, 512, 512, 512, 0, 0, 0, 1, 1.f, b_proj);
}

// Round 13
// 370.219 us; speedup vs baseline: 1.1316x; 1.0120x over previous
//
#include <hip/hip_runtime.h>
#include <hip/hip_bf16.h>

typedef __attribute__((ext_vector_type(8))) short short8;
typedef __attribute__((ext_vector_type(4))) float f32x4;
typedef __hip_bfloat16 bf16;
typedef unsigned short ushort;

__device__ __forceinline__ ushort f2b(float v) {
    bf16 h = __float2bfloat16(v);
    return *reinterpret_cast<ushort*>(&h);
}
__device__ __forceinline__ float b2f(ushort u) {
    return __uint_as_float((unsigned)u << 16);
}

#define GLD16(lds, gp) __builtin_amdgcn_global_load_lds( \
    (const __attribute__((address_space(1))) void*)(gp), \
    (__attribute__((address_space(3))) void*)(lds), 16, 0, 0)

// XCD-affinity swizzle (R3-verified: gate FETCH 64.6->37MB). Bijective when
// gridDim.y%8==0 and z==1; otherwise identity. Perf heuristic only.
__device__ __forceinline__ void xcd_swizzle(int& bx, int& by) {
    if (gridDim.z == 1 && (gridDim.y & 7) == 0) {
        const int id = bx + gridDim.x * by;
        const int xcd = id & 7, slot = id >> 3;
        by = xcd * (gridDim.y >> 3) + slot / gridDim.x;
        bx = slot - (slot / gridDim.x) * gridDim.x;
    }
}

// ---------------------------------------------------------------------------
// bf16 MFMA GEMM: C = alpha * A @ B^T (+ bias) with fused epilogues.
// R12 staged core (R4/R15 proved operand-direct is worse: loads issued
// inside the compute phase expose latency serially). Coalesced row-major
// [r][32] chunk-rotation LDS layout (bank-conflict 0). 2-phase double-
// buffer, one __syncthreads per phase, all loads a full phase ahead.
// TM=64: BK=64 phases (2 planes/buffer). TM=128: BK=32 (m132).
// R17 TN=64 variant (VERIFIED R12: -6us): 32x32 wave quadrants, 1
// B-GLD16/wave, for GRID-STARVED dispatches (1-1.5 blocks/CU = near-zero
// TLP; smaller tiles double block count). Same k-chunk order -> outputs
// bit-identical. Pipe-bound dispatches keep TN=128.
// EPI 0: plain.
// EPI 4: QKV head-scatter: C=Qb, px=Kb, py=VT   [b][h][n][hd] / [b][h][hd][n]
// EPI 5: KV split: C=Kc [b][n][512], py=v_iT [b][hd][768]
// EPI 6: dual write: C normal + py transposed (eld=transposed ld, sE=batch str)
// EPI 7: batched-pair: z<16 uses (A,lda,sA,B,ldb,sB); z>=16 uses
//        (px,lda2,sA2, py,eld,sB=0)  [z>=16 = x2 @ G^T]
// ---------------------------------------------------------------------------
template<typename OutT, int EPI, int TM, int TN = 128>
__global__ __launch_bounds__(256) void gemm_bf16(
    const bf16* __restrict__ A, const bf16* __restrict__ B, OutT* __restrict__ C,
    int K, int lda, int ldb, int ldc, long sA, long sB, long sC,
    float alpha, const float* __restrict__ bias,
    int lda2, long sA2, int eld, long sE,
    bf16* __restrict__ px, bf16* __restrict__ py)
{
    constexpr int RT = TM / 32;              // row MFMA-tiles per wave
    constexpr int CT = TN / 32;              // col MFMA-tiles per wave
    constexpr int PLA = TM * 32;             // halfwords per 32-k A plane
    constexpr int PLB = TN * 32;
    constexpr int NP = (TM == 64) ? 4 : 2;   // planes total (2 bufs x {2,1})
    __shared__ __align__(16) bf16 As[NP * PLA];
    __shared__ __align__(16) bf16 Bs[NP * PLB];

    const int t = threadIdx.x;
    const int w = t >> 6, lane = t & 63;
    const int wr = w >> 1, wc = w & 1;
    const int lr = lane & 15, kc4 = lane >> 4;
    const int qr = lane >> 2;                              // row within 16-row slice
    const int kcr = ((lane & 3) - ((lane >> 3) & 3)) & 3;  // rotated global k-chunk
    int bx = blockIdx.x, by = blockIdx.y;
    xcd_swizzle(bx, by);
    const int row0 = by * TM, col0 = bx * TN;
    const int bz = blockIdx.z;

    const bf16* Asel = A; const bf16* Bsel = B;
    int abz = bz; long sBe = sB, sAe = sA; int ldbe = ldb, ldae = lda;
    if constexpr (EPI == 7) {
        if (bz >= 16) {
            Asel = (const bf16*)px; Bsel = (const bf16*)py;
            abz = bz - 16; sBe = 0; ldbe = eld; ldae = lda2; sAe = sA2;
        }
    }
    const bf16* Ab = Asel + (size_t)abz * sAe + (size_t)row0 * ldae;
    const bf16* Bb = Bsel + (size_t)abz * sBe + (size_t)col0 * ldbe;

    // staging: each GLD16 covers 16 rows x 64B (4 lanes/row, coalesced)
    const bf16* ga0; const bf16* ga1 = nullptr;
    if constexpr (TM == 64) {
        ga0 = Ab + (size_t)(w * 16 + qr) * ldae + kcr * 8;
    } else {
        ga0 = Ab + (size_t)(w * 32 + qr) * ldae + kcr * 8;
        ga1 = Ab + (size_t)(w * 32 + 16 + qr) * ldae + kcr * 8;
    }
    const bf16* gb0; const bf16* gb1 = nullptr;
    if constexpr (TN == 128) {
        gb0 = Bb + (size_t)(w * 32 + qr) * ldbe + kcr * 8;
        gb1 = Bb + (size_t)(w * 32 + 16 + qr) * ldbe + kcr * 8;
    } else {
        gb0 = Bb + (size_t)(w * 16 + qr) * ldbe + kcr * 8;
    }
    bf16* lA0; bf16* lA1 = nullptr;
    if constexpr (TM == 64) { lA0 = &As[w * 512]; }
    else                    { lA0 = &As[w * 1024]; lA1 = &As[w * 1024 + 512]; }
    bf16* lB0; bf16* lB1 = nullptr;
    if constexpr (TN == 128) { lB0 = &Bs[w * 1024]; lB1 = &Bs[w * 1024 + 512]; }
    else                     { lB0 = &Bs[w * 512]; }

    f32x4 acc[RT][CT] = {};

    const int cSw = ((kc4 + ((lr >> 1) & 3)) & 3) * 8;     // swizzled chunk offset
    const bf16* ApBase = &As[(wr * (TM / 2) + lr) * 32 + cSw];
    const bf16* BpBase = &Bs[(wc * (TN / 2) + lr) * 32 + cSw];

    auto stageP = [&](int plane, int ko) {
        GLD16(lA0 + plane * PLA, ga0 + ko);
        if constexpr (TM == 128) GLD16(lA1 + plane * PLA, ga1 + ko);
        GLD16(lB0 + plane * PLB, gb0 + ko);
        if constexpr (TN == 128) GLD16(lB1 + plane * PLB, gb1 + ko);
    };
    auto compP = [&](int plane) {
        const bf16* Ap = ApBase + plane * PLA;
        const bf16* Bp = BpBase + plane * PLB;
        short8 af[RT], bfr[CT];
#pragma unroll
        for (int i = 0; i < RT; ++i) af[i]  = *(const short8*)(Ap + i * 512);
#pragma unroll
        for (int j = 0; j < CT; ++j) bfr[j] = *(const short8*)(Bp + j * 512);
#pragma unroll
        for (int i = 0; i < RT; ++i)
#pragma unroll
            for (int j = 0; j < CT; ++j)
                acc[i][j] = __builtin_amdgcn_mfma_f32_16x16x32_bf16(af[i], bfr[j], acc[i][j], 0, 0, 0);
    };

    if constexpr (TM == 64) {
        stageP(0, 0); stageP(1, 32);        // prologue: buffer 0, planes 0..1
        int buf = 0;
        for (int k0 = 0; k0 < K; k0 += 64) {   // K % 64 == 0 at all call sites
            __syncthreads();                   // cur buf staged; other buf free
            if (k0 + 64 < K) {
                stageP((buf ^ 1) * 2,     k0 + 64);
                stageP((buf ^ 1) * 2 + 1, k0 + 96);
            }
            compP(buf * 2); compP(buf * 2 + 1);
            buf ^= 1;
        }
    } else {
        stageP(0, 0);
        int buf = 0;
        for (int k0 = 0; k0 < K; k0 += 32) {
            __syncthreads();
            if (k0 + 32 < K) stageP(buf ^ 1, k0 + 32);
            compP(buf);
            buf ^= 1;
        }
    }

    if constexpr (EPI == 4) {
        const int sec = bx >> 2;                    // 0=q 1=k 2=v
        const int h0 = (bx & 3) * 2;
        const int b  = by / 6;
        const int n0 = (by % 6) * TM;
        bf16* dq = (bf16*)C;
#pragma unroll
        for (int j = 0; j < CT; ++j) {
            const int col = wc * 64 + j * 16 + lr;
            const int h = h0 + (col >> 6), hd = col & 63;
            const size_t bh = (size_t)b * 8 + h;
#pragma unroll
            for (int i = 0; i < RT; ++i) {
                const int n = n0 + wr * (TM / 2) + i * 16 + kc4 * 4;
                if (sec == 2) {
                    __align__(8) ushort o[4];
#pragma unroll
                    for (int r = 0; r < 4; ++r) o[r] = f2b(acc[i][j][r]);
                    *(int2*)&py[(bh * 64 + hd) * 768 + n] = *(const int2*)o;
                } else {
                    bf16* d = (sec == 0) ? dq : px;
#pragma unroll
                    for (int r = 0; r < 4; ++r)
                        d[(bh * 768 + n + r) * 64 + hd] = __float2bfloat16(acc[i][j][r]);
                }
            }
        }
        return;
    } else if constexpr (EPI == 5) {
        const int b  = by / 6;
        const int n0 = (by % 6) * TM;
#pragma unroll
        for (int j = 0; j < CT; ++j) {
            const int col = col0 + wc * 64 + j * 16 + lr;
#pragma unroll
            for (int i = 0; i < RT; ++i) {
                const int n = n0 + wr * (TM / 2) + i * 16 + kc4 * 4;
                if (col < 512) {
#pragma unroll
                    for (int r = 0; r < 4; ++r)
                        ((bf16*)C)[((size_t)b * 768 + n + r) * 512 + col] = __float2bfloat16(acc[i][j][r]);
                } else {
                    __align__(8) ushort o[4];
#pragma unroll
                    for (int r = 0; r < 4; ++r) o[r] = f2b(acc[i][j][r]);
                    *(int2*)&py[((size_t)b * 512 + (col - 512)) * 768 + n] = *(const int2*)o;
                }
            }
        }
        return;
    }

    OutT* Cb = C + (size_t)bz * sC;
#pragma unroll
    for (int j = 0; j < CT; ++j) {
        const int col = col0 + wc * (TN / 2) + j * 16 + lr;
        const float bv = bias ? bias[col] : 0.f;
#pragma unroll
        for (int i = 0; i < RT; ++i) {
            const int rb = row0 + wr * (TM / 2) + i * 16 + kc4 * 4;
            if constexpr (EPI == 6) {
                __align__(8) ushort o[4];
#pragma unroll
                for (int r = 0; r < 4; ++r) {
                    o[r] = f2b(alpha * acc[i][j][r]);
                    Cb[(size_t)(rb + r) * ldc + col] = __float2bfloat16(alpha * acc[i][j][r]);
                }
                *(int2*)&py[(size_t)bz * sE + (size_t)col * eld + rb] = *(const int2*)o;
            } else {
#pragma unroll
                for (int r = 0; r < 4; ++r) {
                    const int row = rb + r;
                    float v = alpha * acc[i][j][r] + bv;
                    if constexpr (sizeof(OutT) == 2)
                        Cb[(size_t)row * ldc + col] = __float2bfloat16(v);
                    else
                        Cb[(size_t)row * ldc + col] = v;
                }
            }
        }
    }
}

// ---------------------------------------------------------------------------
// Fused gate GEMM (steps 11+12).
// R18: TN=64 col-split (same mechanism R12 verified on steps 1/1b/4/5):
// grid (8,192) = 1536 blocks (~5-6 blk/CU vs 3), wave quadrants 32x32,
// acc arrays halved (VGPR down), LDS 24KB. Per 32-k phase: stage A(1)+
// F(1)+M(1 while k<512) GLD16/wave; compute 4 F-MFMA (+4 M-MFMA sharing
// A fragments). Same k-chunk order per output -> bit-identical. Cost:
// A staged by 8 col-blocks (L2-hit, XCD-pinned); TLP wins for this
// latency-bound dispatch (all pipes <15% at 3 blk/CU).
// ---------------------------------------------------------------------------
__global__ __launch_bounds__(256) void gemm_gate(
    const bf16* __restrict__ A, const bf16* __restrict__ Bf,
    const bf16* __restrict__ Bm, bf16* __restrict__ Cout,
    const float* __restrict__ bias_f, const float* __restrict__ bias_m,
    const float* __restrict__ x1)
{
    constexpr int AHW = 64 * 32;
    constexpr int BHW = 64 * 32;
    __shared__ __align__(16) bf16 As[2 * AHW];
    __shared__ __align__(16) bf16 FsS[2 * BHW];
    __shared__ __align__(16) bf16 MsS[2 * BHW];

    const int t = threadIdx.x;
    const int w = t >> 6, lane = t & 63;
    const int wr = w >> 1, wc = w & 1;
    const int lr = lane & 15, kc4 = lane >> 4;
    const int qr = lane >> 2;
    const int kcr = ((lane & 3) - ((lane >> 3) & 3)) & 3;
    int bx = blockIdx.x, by = blockIdx.y;
    xcd_swizzle(bx, by);
    const int row0 = by * 64, col0 = bx * 64;

    const bf16* ga0 = A  + (size_t)(row0 + w * 16 + qr) * 1024 + kcr * 8;
    const bf16* gf0 = Bf + (size_t)(col0 + w * 16 + qr) * 1024 + kcr * 8;
    const bf16* gm0 = Bm + (size_t)(col0 + w * 16 + qr) * 512 + kcr * 8;
    bf16* lA0 = &As[w * 512];
    bf16* lF0 = &FsS[w * 512];
    bf16* lM0 = &MsS[w * 512];

    f32x4 acc1[2][2] = {};   // fg
    f32x4 acc2[2][2] = {};   // hm

    const int cSw = ((kc4 + ((lr >> 1) & 3)) & 3) * 8;
    const bf16* ApBase = &As[(wr * 32 + lr) * 32 + cSw];
    const bf16* FpBase = &FsS[(wc * 32 + lr) * 32 + cSw];
    const bf16* MpBase = &MsS[(wc * 32 + lr) * 32 + cSw];

    // prologue: stage k=0 into buffer 0
    GLD16(lA0, ga0);
    GLD16(lF0, gf0);
    GLD16(lM0, gm0);

    auto step = [&](int kk, int rd, int st) {
        __syncthreads();
        const int kn = kk + 32;
        if (kn < 1024) {
            GLD16(lA0 + st * AHW, ga0 + kn);
            GLD16(lF0 + st * BHW, gf0 + kn);
            if (kn < 512) GLD16(lM0 + st * BHW, gm0 + kn);
        }
        const bf16* Ap = ApBase + rd * AHW;
        const bf16* Fp = FpBase + rd * BHW;
        short8 af[2], ff[2];
#pragma unroll
        for (int i = 0; i < 2; ++i) af[i] = *(const short8*)(Ap + i * 512);
#pragma unroll
        for (int j = 0; j < 2; ++j) ff[j] = *(const short8*)(Fp + j * 512);
#pragma unroll
        for (int i = 0; i < 2; ++i)
#pragma unroll
            for (int j = 0; j < 2; ++j)
                acc1[i][j] = __builtin_amdgcn_mfma_f32_16x16x32_bf16(af[i], ff[j], acc1[i][j], 0, 0, 0);
        if (kk < 512) {
            const bf16* Mp = MpBase + rd * BHW;
            short8 mf[2];
#pragma unroll
            for (int j = 0; j < 2; ++j) mf[j] = *(const short8*)(Mp + j * 512);
#pragma unroll
            for (int i = 0; i < 2; ++i)
#pragma unroll
                for (int j = 0; j < 2; ++j)
                    acc2[i][j] = __builtin_amdgcn_mfma_f32_16x16x32_bf16(af[i], mf[j], acc2[i][j], 0, 0, 0);
        }
    };

    for (int k0 = 0; k0 < 1024; k0 += 64) {
        step(k0, 0, 1);
        step(k0 + 32, 1, 0);
    }

#pragma unroll
    for (int j = 0; j < 2; ++j) {
        const int col = col0 + wc * 32 + j * 16 + lr;
        const float bvf = bias_f[col], bvm = bias_m[col];
#pragma unroll
        for (int i = 0; i < 2; ++i) {
            const int rb = row0 + wr * 32 + i * 16 + kc4 * 4;
#pragma unroll
            for (int r = 0; r < 4; ++r) {
                const int row = rb + r;
                const float sig = 1.f / (1.f + __expf(-(acc1[i][j][r] + bvf)));
                const float rr = x1[(size_t)row * 512 + col] + (acc2[i][j][r] + bvm) * sig;
                Cout[(size_t)row * 512 + col] = __float2bfloat16(rr > 0.f ? rr : 0.f);
            }
        }
    }
}

// ---------------------------------------------------------------------------
// Transpose + cast to bf16: src [R,C] -> dst [C,R] bf16. Multi-source via z.
// rep/repStride: replicate the transposed output (for broadcast B panels).
// ---------------------------------------------------------------------------
template<typename TI, int NSRC>
__global__ __launch_bounds__(256) void k_transpose(
    const TI* __restrict__ s0, const TI* __restrict__ s1,
    const TI* __restrict__ s2, const TI* __restrict__ s3,
    bf16* __restrict__ dst, int src_ld, int dst_ld, long sSrc, long sDst,
    int rep, long repStride)
{
    __shared__ float tile[64][65];
    const int t = threadIdx.x;
    const int c0 = blockIdx.x * 64, r0 = blockIdx.y * 64;
    const int z = blockIdx.z;
    const TI* src = s0;
    if (NSRC > 1) src = (z == 0) ? s0 : (z == 1) ? s1 : (z == 2) ? s2 : s3;
    {
        const int r = t >> 2, cq = (t & 3) * 16;
        const TI* sp = src + (size_t)z * sSrc + (size_t)(r0 + r) * src_ld + c0 + cq;
        if constexpr (sizeof(TI) == 4) {
#pragma unroll
            for (int u = 0; u < 16; u += 4) {
                float4 v = *(const float4*)((const float*)sp + u);
                tile[r][cq + u]     = v.x; tile[r][cq + u + 1] = v.y;
                tile[r][cq + u + 2] = v.z; tile[r][cq + u + 3] = v.w;
            }
        } else {
            const ushort* up = (const ushort*)sp;
            union { short8 v; ushort u[8]; } p0, p1;
            p0.v = *(const short8*)up; p1.v = *(const short8*)(up + 8);
#pragma unroll
            for (int u = 0; u < 8; ++u) {
                tile[r][cq + u]     = b2f(p0.u[u]);
                tile[r][cq + 8 + u] = b2f(p1.u[u]);
            }
        }
    }
    __syncthreads();
    const int c = t >> 2, rq = (t & 3) * 16;
    __align__(16) ushort ob[16];
#pragma unroll
    for (int u = 0; u < 16; ++u) ob[u] = f2b(tile[rq + u][c]);
    for (int rp = 0; rp < rep; ++rp) {
        bf16* dp = dst + (size_t)rp * repStride + (size_t)z * sDst + (size_t)(c0 + c) * dst_ld + r0 + rq;
        *(int4*)dp       = *(const int4*)&ob[0];
        *(int4*)(dp + 8) = *(const int4*)&ob[8];
    }
}

// input casts in one dispatch (z selects job). z==3: strided read of
// Wqkv_j[:, :512] (f32 ld 1536) -> Wj_bf [512][512] bf16 (for the G trick).
__global__ __launch_bounds__(256) void k_cast3(const float* __restrict__ x1,
    const float* __restrict__ x2, const float* __restrict__ zb,
    const float* __restrict__ wj,
    bf16* __restrict__ d1, bf16* __restrict__ d2, bf16* __restrict__ d3,
    bf16* __restrict__ d4)
{
    const int z = blockIdx.z;
    const float* src; bf16* dst; int ld; float scale; int n;
    if (z == 0)      { src = x1; dst = d1; ld = 512;  scale = 1.f;  n = 6291456; }
    else if (z == 1) { src = x2; dst = d2; ld = 1024; scale = 1.f;  n = 6291456; }
    else if (z == 2) { src = zb; dst = d3; ld = 512;  scale = 0.2f; n = 131072;  }
    else             { src = wj; dst = d4; ld = 512;  scale = 1.f;  n = 262144;  }
    int i = (blockIdx.x * 256 + threadIdx.x) * 8;
    if (i >= n) return;
    int si = i;
    if (z == 3) si = (i >> 9) * 1536 + (i & 511);
    float4 a = *(const float4*)(src + si), b = *(const float4*)(src + si + 4);
    __align__(16) ushort o[8];
    o[0] = f2b(a.x * scale); o[1] = f2b(a.y * scale); o[2] = f2b(a.z * scale); o[3] = f2b(a.w * scale);
    o[4] = f2b(b.x * scale); o[5] = f2b(b.y * scale); o[6] = f2b(b.z * scale); o[7] = f2b(b.w * scale);
    int row = i >> 9, col = i & 511;
    *(int4*)(dst + (size_t)row * ld + col) = *(const int4*)o;
}

// ---------------------------------------------------------------------------
// Wave-per-row softmax f32 -> bf16. 4 rows/block (one per wave), no barriers.
// MODE 0: dst = Y + row*COLS.
// MODE 1 (merged S2/S3, COLS=256): row = z*768+m, z in [0,32);
//   dst = Y + ((z&15)*768+m)*512 + (z>>4)*256   (K-concat layout).
// ---------------------------------------------------------------------------
template<int COLS, int MODE>
__global__ __launch_bounds__(256) void softmax_wave(const float* __restrict__ X,
                                                    bf16* __restrict__ Y)
{
    const int wv = threadIdx.x >> 6, lane = threadIdx.x & 63;
    const long row = (long)blockIdx.x * 4 + wv;
    const float* src = X + row * COLS;
    constexpr int V = COLS / 64;
    float v[V];
#pragma unroll
    for (int i = 0; i < V; ++i) v[i] = src[lane + i * 64];
    float m = v[0];
#pragma unroll
    for (int i = 1; i < V; ++i) m = fmaxf(m, v[i]);
#pragma unroll
    for (int o = 32; o; o >>= 1) m = fmaxf(m, __shfl_xor(m, o));
    float s = 0.f;
#pragma unroll
    for (int i = 0; i < V; ++i) { v[i] = __expf(v[i] - m); s += v[i]; }
#pragma unroll
    for (int o = 32; o; o >>= 1) s += __shfl_xor(s, o);
    const float inv = 1.f / s;
    bf16* dst;
    if constexpr (MODE == 0) {
        dst = Y + row * COLS;
    } else {
        const int z = (int)(row / 768), mm = (int)(row % 768);
        dst = Y + ((size_t)(z & 15) * 768 + mm) * 512 + (z >> 4) * 256;
    }
#pragma unroll
    for (int i = 0; i < V; ++i) dst[lane + i * 64] = __float2bfloat16(v[i] * inv);
}

// ---------------------------------------------------------------------------
// MFMA flash MHSA v4 (verified R7): no online max (scores O(1), exp safe),
// unnormalized P accumulation, single end reduction. Head-separated inputs,
// head-major grid for L2 pinning.
// ---------------------------------------------------------------------------
__global__ __launch_bounds__(256) void mhsa_flash_mfma(
    const bf16* __restrict__ Qb, const bf16* __restrict__ Kb,
    const bf16* __restrict__ VT, bf16* __restrict__ Hout)
{
    constexpr int LD = 72;
    __shared__ __align__(16) ushort Qs[64 * LD];
    __shared__ __align__(16) ushort Ks[64 * LD];
    __shared__ __align__(16) ushort Vt[64 * LD];
    __shared__ __align__(16) ushort Ps[64 * LD];

    const int t = threadIdx.x;
    const int w = t >> 6, lane = t & 63;
    const int l16 = lane & 15, q4 = lane >> 4;
    const int h = blockIdx.x, b = blockIdx.y, qt = blockIdx.z;
    const size_t bh = (size_t)b * 8 + h;
    const ushort* qbase = (const ushort*)Qb + bh * 768 * 64;
    const ushort* kbase = (const ushort*)Kb + bh * 768 * 64;
    const ushort* vbase = (const ushort*)VT + bh * 64 * 768;

    const int r = t >> 2, c0 = (t & 3) * 16;

    {
        const ushort* src = qbase + (size_t)(qt * 64 + r) * 64 + c0;
        *(int4*)&Qs[r * LD + c0]     = *(const int4*)src;
        *(int4*)&Qs[r * LD + c0 + 8] = *(const int4*)(src + 8);
    }

    int4 ka0, ka1, va0, va1;
    {
        const ushort* ks = kbase + (size_t)r * 64 + c0;
        ka0 = *(const int4*)ks; ka1 = *(const int4*)(ks + 8);
        const ushort* vs = vbase + (size_t)r * 768 + c0;
        va0 = *(const int4*)vs; va1 = *(const int4*)(vs + 8);
    }
    __syncthreads();

    short8 qf0 = *(const short8*)&Qs[(w * 16 + l16) * LD + q4 * 8];
    short8 qf1 = *(const short8*)&Qs[(w * 16 + l16) * LD + 32 + q4 * 8];

    float lsum[4] = {0.f, 0.f, 0.f, 0.f};
    f32x4 acc[4] = {};

    for (int kt = 0; kt < 12; ++kt) {
        if (kt) __syncthreads();
        *(int4*)&Ks[r * LD + c0]     = ka0;
        *(int4*)&Ks[r * LD + c0 + 8] = ka1;
        *(int4*)&Vt[r * LD + c0]     = va0;
        *(int4*)&Vt[r * LD + c0 + 8] = va1;
        __syncthreads();

        if (kt < 11) {
            const ushort* ks = kbase + (size_t)((kt + 1) * 64 + r) * 64 + c0;
            ka0 = *(const int4*)ks; ka1 = *(const int4*)(ks + 8);
            const ushort* vs = vbase + (size_t)r * 768 + (kt + 1) * 64 + c0;
            va0 = *(const int4*)vs; va1 = *(const int4*)(vs + 8);
        }

        f32x4 s[4] = {};
#pragma unroll
        for (int nt = 0; nt < 4; ++nt) {
            short8 kf0 = *(const short8*)&Ks[(nt * 16 + l16) * LD + q4 * 8];
            short8 kf1 = *(const short8*)&Ks[(nt * 16 + l16) * LD + 32 + q4 * 8];
            s[nt] = __builtin_amdgcn_mfma_f32_16x16x32_bf16(qf0, kf0, s[nt], 0, 0, 0);
            s[nt] = __builtin_amdgcn_mfma_f32_16x16x32_bf16(qf1, kf1, s[nt], 0, 0, 0);
        }

#pragma unroll
        for (int nt = 0; nt < 4; ++nt) {
#pragma unroll
            for (int e = 0; e < 4; ++e) {
                const float p = __expf(s[nt][e] * 0.125f);
                lsum[e] += p;
                Ps[(w * 16 + q4 * 4 + e) * LD + nt * 16 + l16] = f2b(p);
            }
        }

        short8 pf0 = *(const short8*)&Ps[(w * 16 + l16) * LD + q4 * 8];
        short8 pf1 = *(const short8*)&Ps[(w * 16 + l16) * LD + 32 + q4 * 8];
#pragma unroll
        for (int jt = 0; jt < 4; ++jt) {
            short8 vf0 = *(const short8*)&Vt[(jt * 16 + l16) * LD + q4 * 8];
            short8 vf1 = *(const short8*)&Vt[(jt * 16 + l16) * LD + 32 + q4 * 8];
            acc[jt] = __builtin_amdgcn_mfma_f32_16x16x32_bf16(pf0, vf0, acc[jt], 0, 0, 0);
            acc[jt] = __builtin_amdgcn_mfma_f32_16x16x32_bf16(pf1, vf1, acc[jt], 0, 0, 0);
        }
    }

    const int orow = qt * 64 + w * 16 + q4 * 4;
#pragma unroll
    for (int e = 0; e < 4; ++e) {
        float l = lsum[e];
        l += __shfl_xor(l, 1);
        l += __shfl_xor(l, 2);
        l += __shfl_xor(l, 4);
        l += __shfl_xor(l, 8);
        const float inv = 1.f / l;
        const size_t rbase = ((size_t)b * 768 + orow + e) * 512 + h * 64;
#pragma unroll
        for (int jt = 0; jt < 4; ++jt)
            Hout[rbase + jt * 16 + l16] = __float2bfloat16(acc[jt][e] * inv);
    }
}

// ---------------------------------------------------------------------------
extern "C" void kernel_launch(void* const* d_in, const int* in_sizes, int n_in,
                              void* d_out, int out_size, void* d_ws, size_t ws_size,
                              hipStream_t stream)
{
    (void)in_sizes; (void)n_in; (void)out_size; (void)ws_size;
    const float* x1     = (const float*)d_in[0];
    const float* x2     = (const float*)d_in[1];
    const float* z_b    = (const float*)d_in[2];
    const float* Wqkv_i = (const float*)d_in[3];
    const float* Wqkv_j = (const float*)d_in[4];
    const float* Wqkv_b = (const float*)d_in[5];
    const float* W_f    = (const float*)d_in[6];
    const float* b_f    = (const float*)d_in[7];
    const float* W_m    = (const float*)d_in[8];
    const float* b_m    = (const float*)d_in[9];
    const float* W_QKV  = (const float*)d_in[10];
    const float* W_proj = (const float*)d_in[11];
    const float* b_proj = (const float*)d_in[12];
    float* out = (float*)d_out;

    const float scale = 0.044194173824159216f;   // 512^-0.5

    char* base = (char*)d_ws;
    size_t off = 0;
    auto alloc = [&](size_t bytes) { char* r = base + off; off += (bytes + 255) & ~(size_t)255; return r; };

    char* Rq  = alloc((size_t)3 * 25165824);
    char* R1  = Rq;                 // Kc bf16 | Qb+Kb bf16
    char* R2  = Rq + 25165824;      // v_iT bf16 | VTb bf16
    char* R3  = Rq + 2 * 25165824;  // c_x1 bf16
    char* R4  = alloc(25165824);    // Hout bf16
    bf16* Wt4     = (bf16*)alloc((size_t)3 * 1536 * 512 * 2);  // i, b, qkv
    bf16* Wt_f    = (bf16*)alloc(512 * 1024 * 2);
    bf16* Wt_mp   = (bf16*)alloc((size_t)2 * 512 * 512 * 2);   // m, proj
    bf16* Wj_bf   = (bf16*)alloc(512 * 512 * 2);               // Wqkv_j[:, :512] bf16
    bf16* Gbuf    = (bf16*)alloc(256 * 512 * 2);               // G = k_b @ Wj^T
    bf16* c_zb    = (bf16*)alloc(256 * 512 * 2);
    bf16* qkvb    = (bf16*)alloc(256 * 1536 * 2);
    bf16* aib0    = (bf16*)alloc((size_t)16 * 256 * 512 * 2);
    bf16* Bcat    = (bf16*)alloc((size_t)16 * 512 * 512 * 2);  // [aib0^T | v_b^T]
    float* S      = (float*)alloc((size_t)32 * 768 * 256 * 4);
    bf16* Sb1     = (bf16*)alloc((size_t)16 * 256 * 768 * 2);
    bf16* Sb_cat  = (bf16*)alloc((size_t)16 * 768 * 512 * 2);  // [P2 | P3] K-concat
    bf16* c_cat   = (bf16*)alloc((size_t)12288 * 1024 * 2);
    bf16* hbuf    = (bf16*)alloc((size_t)12288 * 512 * 2);

    bf16* Wt_i = Wt4, *Wt_b = Wt4 + 1536 * 512,
        *Wt_qkv = Wt4 + (size_t)2 * 1536 * 512;
    bf16* Wt_m = Wt_mp, *Wt_proj = Wt_mp + 512 * 512;

    bf16*  Kc   = (bf16*)R1;                 // [16][768][512]
    bf16*  Qb   = (bf16*)R1;                 // [16][8][768][64] (after Kc dead)
    bf16*  Kb   = (bf16*)(R1 + 12582912);
    bf16*  v_iT = (bf16*)R2;                 // [16][512][768]
    bf16*  VTb  = (bf16*)R2;                 // [16][8][64][768] (after v_iT dead)
    bf16*  c_x1 = (bf16*)R3;
    bf16*  Hout = (bf16*)R4;

    // TM=64 plain GEMM launcher (TN=128)
    auto G64 = [&](const bf16* A, const bf16* B, void* C, bool outBf,
                   int M, int N, int K, int lda, int ldb, int ldc,
                   long sA, long sB, long sC, int batch, float alpha, const float* bias) {
        dim3 grid(N / 128, M / 64, batch);
        if (outBf) gemm_bf16<bf16, 0, 64><<<grid, 256, 0, stream>>>(A, B, (bf16*)C, K, lda, ldb, ldc, sA, sB, sC, alpha, bias, 0, 0, 0, 0, nullptr, nullptr);
        else       gemm_bf16<float, 0, 64><<<grid, 256, 0, stream>>>(A, B, (float*)C, K, lda, ldb, ldc, sA, sB, sC, alpha, bias, 0, 0, 0, 0, nullptr, nullptr);
    };
    // TN=64 launcher for grid-starved dispatches (2x blocks)
    auto G64n = [&](const bf16* A, const bf16* B, void* C, bool outBf,
                    int M, int N, int K, int lda, int ldb, int ldc,
                    long sA, long sB, long sC, int batch, float alpha, const float* bias) {
        dim3 grid(N / 64, M / 64, batch);
        if (outBf) gemm_bf16<bf16, 0, 64, 64><<<grid, 256, 0, stream>>>(A, B, (bf16*)C, K, lda, ldb, ldc, sA, sB, sC, alpha, bias, 0, 0, 0, 0, nullptr, nullptr);
        else       gemm_bf16<float, 0, 64, 64><<<grid, 256, 0, stream>>>(A, B, (float*)C, K, lda, ldb, ldc, sA, sB, sC, alpha, bias, 0, 0, 0, 0, nullptr, nullptr);
    };

    // ---- stage 0: one cast dispatch (x1, x2, zb, Wj) + 3 transposes ----
    k_cast3<<<dim3(3072, 1, 4), 256, 0, stream>>>(x1, x2, z_b, Wqkv_j,
                                                  c_x1, c_cat + 512, c_zb, Wj_bf);
    k_transpose<float, 3><<<dim3(24, 8, 3), 256, 0, stream>>>(
        Wqkv_i, Wqkv_b, W_QKV, nullptr, Wt4, 1536, 512, 0, 1536L * 512, 1, 0);
    k_transpose<float, 1><<<dim3(8, 16, 1), 256, 0, stream>>>(
        W_f, nullptr, nullptr, nullptr, Wt_f, 512, 1024, 0, 0, 1, 0);
    k_transpose<float, 2><<<dim3(8, 8, 2), 256, 0, stream>>>(
        W_m, W_proj, nullptr, nullptr, Wt_mp, 512, 512, 0, 512L * 512, 1, 0);

    // 1. qkvb = (0.2 zb) @ Wqkv_b   [256,1536] bf16   [TN=64: 96 blocks]
    G64n(c_zb, Wt_b, qkvb, true, 256, 1536, 512, 512, 512, 1536, 0, 0, 0, 1, 1.f, nullptr);
    // 1b. G = k_b @ Wj^T  [256,512] bf16  (S3 = x2@G^T)  [TN=64: 32 blk]
    G64n(qkvb + 512, Wj_bf, Gbuf, true, 256, 512, 512, 1536, 512, 512, 0, 0, 0, 1, 1.f, nullptr);
    // v_b^T -> Bcat[:, :, 256:512], replicated over all 16 batches
    k_transpose<bf16, 1><<<dim3(8, 4, 1), 256, 0, stream>>>(
        qkvb + 1024, nullptr, nullptr, nullptr, Bcat + 256, 1536, 512, 0, 0, 16, 512L * 512);
    // 2. [k_i|v_i] = x1 @ Wqkv_i[:,512:]  -> Kc compact + v_iT transposed
    gemm_bf16<bf16, 5, 128><<<dim3(8, 96, 1), 256, 0, stream>>>(
        c_x1, Wt_i + 512 * 512, Kc, 512, 512, 512, 512, 0, 0, 0,
        1.f, nullptr, 0, 0, 0, 0, nullptr, v_iT);
    // 4. S1 = scale * q_b @ k_i^T  [16][256,768] f32  [TN=64: 768 blk]
    G64n(qkvb, Kc, S, false, 256, 768, 512, 1536, 512, 768, 0, 768L * 512, 256L * 768, 16, scale, nullptr);
    softmax_wave<768, 0><<<1024, 256, 0, stream>>>(S, Sb1);
    // 5. aib0 = softmax1 @ v_i -> aib0 + Bcat[:,:,0:256]  [TN=64: 512 blk]
    gemm_bf16<bf16, 6, 64, 64><<<dim3(8, 4, 16), 256, 0, stream>>>(
        Sb1, v_iT, aib0, 768, 768, 768, 512, 256L * 768, 512L * 768, 256L * 512,
        1.f, nullptr, 0, 0, 512, 512L * 512, nullptr, Bcat);
    // 6+8. merged S2/S3: z<16: x1 @ aib0^T; z>=16: x2 @ G^T   [32][768,256]
    gemm_bf16<float, 7, 64><<<dim3(2, 12, 32), 256, 0, stream>>>(
        c_x1, aib0, S, 512, 512, 512, 256, 768L * 512, 256L * 512, 768L * 256,
        scale, nullptr, /*lda2=*/1024, /*sA2=*/768L * 1024, /*eld=*/512, 0,
        c_cat + 512, Gbuf);
    softmax_wave<256, 1><<<6144, 256, 0, stream>>>(S, Sb_cat);
    // 7+9+10. a_ij = 0.5 * [P2|P3] @ [aib0; v_b]  -> c_cat[:, :512] bf16
    G64(Sb_cat, Bcat, c_cat, true, 768, 512, 512, 512, 512, 1024,
        768L * 512, 512L * 512, 768L * 1024, 16, 0.5f, nullptr);
    // 11+12. fused gate  [R18: TN=64, grid (8,192) = 1536 blocks]
    gemm_gate<<<dim3(8, 192), 256, 0, stream>>>(c_cat, Wt_f, Wt_m, hbuf, b_f, b_m, x1);
    // 13. QKV = h @ W_QKV -> head-separated Qb/Kb/VTb      [fused scatter]
    gemm_bf16<bf16, 4, 128><<<dim3(12, 96, 1), 256, 0, stream>>>(
        hbuf, Wt_qkv, Qb, 512, 512, 512, 0, 0, 0, 0,
        1.f, nullptr, 0, 0, 0, 0, Kb, VTb);
    // 14. MFMA flash MHSA -> Hout bf16
    mhsa_flash_mfma<<<dim3(8, 16, 12), 256, 0, stream>>>(Qb, Kb, VTb, Hout);
    // 15. out = Hout @ W_proj + b_proj          f32
    G64(Hout, Wt_proj, out, false, 12288, 512, 512, 512, 512, 512, 0, 0, 0, 1, 1.f, b_proj);
}